// Round 7
// baseline (319.309 us; speedup 1.0000x reference)
//
#include <hip/hip_runtime.h>
#include <math.h>
#include <stdint.h>

#define DDIM   256
#define HWSZ   1024
#define NROWS  32768
#define KCODES 1024
#define BD     32
#define NT     256
#define WSP    132

// ws layout: [0,4096) f32 wnorm[1024]; [4096, 4096+262144) u64 keys[32768]
#define WS_WNORM 0
#define WS_KEYS  4096
#define WS_NEED  (4096 + NROWS * 8)

__device__ __forceinline__ uint32_t fbits(float f) { return __float_as_uint(f); }

// ---------------------------------------------------------------------------
// k1: per-code squared norms + zero the loss slot (proven, verbatim)
// ---------------------------------------------------------------------------
__global__ __launch_bounds__(256)
void vq_wnorm(const float* __restrict__ weight, float* __restrict__ wnorm,
              float* __restrict__ loss_slot) {
  const int tid  = threadIdx.x;
  const int lane = tid & 63;
  const int code = blockIdx.x * 4 + (tid >> 6);
  float4 v = *(const float4*)(weight + (size_t)code * DDIM + lane * 4);
  float s = v.x * v.x + v.y * v.y + v.z * v.z + v.w * v.w;
#pragma unroll
  for (int off = 1; off < 64; off <<= 1) s += __shfl_xor(s, off);
  if (lane == 0) wnorm[code] = s;
  if (blockIdx.x == 0 && tid == 0) *loss_slot = 0.0f;
}

// ---------------------------------------------------------------------------
// k2: f32 distances, round-6 arithmetic bit-identical (coarse grid + xn),
// retiled: block = 128 rows x 256 codes (quarter q = bid>>8 -> XCD-grouped),
// thread = 8 rows x 8 codes, xn folded into kt=0, swizzled Ws staging.
// Global merge via u64 atomicMin keys (min dist, lowest code on bit-ties).
// ---------------------------------------------------------------------------
__global__ __launch_bounds__(NT, 4)
void vq_dist(const float* __restrict__ latent, const float* __restrict__ weight,
             const float* __restrict__ wnorm,
             unsigned long long* __restrict__ keys) {
  __shared__ __align__(16) float As[BD][128];   // 16 KB  [dim][row]
  __shared__ __align__(16) float Ws[BD][WSP];   // 16.9 KB [dim][code^swz]

  const int tid = threadIdx.x;
  const int tx  = tid & 15;           // 16 code-groups
  const int ty  = tid >> 4;           // 16 row-groups (8 rows each)
  const int bid = blockIdx.x;
  const int rb  = bid & 255;          // row-block 0..255 (128 rows each)
  const int q   = bid >> 8;           // code quarter 0..3 (same-XCD siblings)
  const int b   = rb >> 3;
  const int hw0 = (rb & 7) * 128;
  const float* lat_b = latent + (size_t)b * DDIM * HWSZ;

  float xn[8] = {0.f,0.f,0.f,0.f,0.f,0.f,0.f,0.f};
  float best[8]; int bidx[8];
#pragma unroll
  for (int r = 0; r < 8; ++r) { best[r] = INFINITY; bidx[r] = 0; }

#pragma unroll
  for (int kt = 0; kt < 2; ++kt) {
    const int k0 = q * 256 + kt * 128;
    float acc[8][8];
#pragma unroll
    for (int r = 0; r < 8; ++r)
#pragma unroll
      for (int c = 0; c < 8; ++c) acc[r][c] = 0.f;

    for (int dc = 0; dc < DDIM / BD; ++dc) {
      const int d0 = dc * BD;
      __syncthreads();
      // stage A chunk: 32 dims x 128 rows (conflict-free float4 writes)
#pragma unroll
      for (int i = 0; i < 4; ++i) {
        int idx = tid + i * NT;
        int dd = idx >> 5, f4 = idx & 31;
        *(float4*)&As[dd][f4 * 4] =
            *(const float4*)(lat_b + (size_t)(d0 + dd) * HWSZ + hw0 + f4 * 4);
      }
      // stage W chunk transposed, col-swizzled: phys = code ^ (row & 24)
#pragma unroll
      for (int i = 0; i < 4; ++i) {
        int idx = tid + i * NT;
        int kl = idx >> 3, df = idx & 7;
        float4 v = *(const float4*)(weight + (size_t)(k0 + kl) * DDIM + d0 + df * 4);
        const int swz = kl ^ ((df >> 1) << 3);   // rows df*4+j: row>>3 == df>>1
        Ws[df * 4 + 0][swz] = v.x;
        Ws[df * 4 + 1][swz] = v.y;
        Ws[df * 4 + 2][swz] = v.z;
        Ws[df * 4 + 3][swz] = v.w;
      }
      __syncthreads();

#pragma unroll 8
      for (int dd = 0; dd < BD; ++dd) {
        const int g8 = dd & 24;                  // read-side unswizzle
        const float* wr = &Ws[dd][0];
        float4 a0 = *(const float4*)&As[dd][ty * 8];
        float4 a1 = *(const float4*)&As[dd][ty * 8 + 4];
        float4 w0 = *(const float4*)(wr + ((tx * 4) ^ g8));        // codes tx*4+0..3
        float4 w1 = *(const float4*)(wr + 64 + ((tx * 4) ^ g8));   // codes 64+tx*4+0..3
        if (kt == 0) {                            // xn: dims ascending, bit-identical
          xn[0] += a0.x * a0.x; xn[1] += a0.y * a0.y;
          xn[2] += a0.z * a0.z; xn[3] += a0.w * a0.w;
          xn[4] += a1.x * a1.x; xn[5] += a1.y * a1.y;
          xn[6] += a1.z * a1.z; xn[7] += a1.w * a1.w;
        }
        float av[8] = {a0.x, a0.y, a0.z, a0.w, a1.x, a1.y, a1.z, a1.w};
        float wv[8] = {w0.x, w0.y, w0.z, w0.w, w1.x, w1.y, w1.z, w1.w};
#pragma unroll
        for (int r = 0; r < 8; ++r)
#pragma unroll
          for (int c = 0; c < 8; ++c)
            acc[r][c] += av[r] * wv[c];
      }
    }

    // distances on the reference's coarse grid (round-6 expression verbatim)
#pragma unroll
    for (int c = 0; c < 8; ++c) {
      const int kg = k0 + ((c < 4) ? (tx * 4 + c) : (64 + tx * 4 + (c - 4)));
      const float wn = wnorm[kg];
#pragma unroll
      for (int r = 0; r < 8; ++r) {
        float dist = (xn[r] + wn) - 2.0f * acc[r][c];
        if (dist < best[r] || (dist == best[r] && kg < bidx[r])) {
          best[r] = dist; bidx[r] = kg;
        }
      }
    }
  }

  // reduce argmin across the 16 code-threads per row; global fold via atomicMin
#pragma unroll
  for (int j = 0; j < 8; ++j) {
    float bd = best[j];
    int   bi = bidx[j];
#pragma unroll
    for (int off = 1; off < 16; off <<= 1) {
      float od = __shfl_xor(bd, off);
      int   oi = __shfl_xor(bi, off);
      if (od < bd || (od == bd && oi < bi)) { bd = od; bi = oi; }
    }
    if (tx == 0) {
      uint32_t db   = fbits(bd);
      uint32_t flip = (db & 0x80000000u) ? ~db : (db | 0x80000000u);
      unsigned long long key =
          ((unsigned long long)flip << 32) | (unsigned long long)(uint32_t)bi;
      atomicMin(&keys[rb * 128 + ty * 8 + j], key);
    }
  }
}

// ---------------------------------------------------------------------------
// k3: keys -> idx, gather codes, transposed coalesced output, loss (proven)
// ---------------------------------------------------------------------------
__global__ __launch_bounds__(256)
void vq_emit(const float* __restrict__ latent, const float* __restrict__ weight,
             const unsigned long long* __restrict__ keys, float* __restrict__ out) {
  __shared__ int   sIdx[64];
  __shared__ float sRed[4];
  const int t   = threadIdx.x;
  const int blk = blockIdx.x;
  const int b   = blk >> 4;
  const int hw0 = (blk & 15) * 64;
  if (t < 64) sIdx[t] = (int)(keys[blk * 64 + t] & 0x3FFull);
  __syncthreads();

  const int hw4  = (t & 15) * 4;
  const int dgrp = t >> 4;
  const float* lat_b = latent + (size_t)b * DDIM * HWSZ;
  float* out_b = out + (size_t)b * DDIM * HWSZ;
  const float* w0 = weight + (size_t)sIdx[hw4 + 0] * DDIM;
  const float* w1 = weight + (size_t)sIdx[hw4 + 1] * DDIM;
  const float* w2 = weight + (size_t)sIdx[hw4 + 2] * DDIM;
  const float* w3 = weight + (size_t)sIdx[hw4 + 3] * DDIM;
  float lsum = 0.f;
#pragma unroll
  for (int it = 0; it < 16; ++it) {
    const int d = it * 16 + dgrp;
    float4 xv = *(const float4*)(lat_b + (size_t)d * HWSZ + hw0 + hw4);
    float q0 = w0[d], q1 = w1[d], q2 = w2[d], q3 = w3[d];
    *(float4*)(out_b + (size_t)d * HWSZ + hw0 + hw4) = make_float4(q0, q1, q2, q3);
    float e0 = q0 - xv.x, e1 = q1 - xv.y, e2 = q2 - xv.z, e3 = q3 - xv.w;
    lsum += e0 * e0 + e1 * e1 + e2 * e2 + e3 * e3;
  }
#pragma unroll
  for (int s = 1; s < 64; s <<= 1) lsum += __shfl_xor(lsum, s);
  if ((t & 63) == 0) sRed[t >> 6] = lsum;
  __syncthreads();
  if (t == 0) {
    float tot = sRed[0] + sRed[1] + sRed[2] + sRed[3];
    atomicAdd(out + (size_t)NROWS * DDIM, tot * (1.0f / 8388608.0f));
  }
}

// ---------------------------------------------------------------------------
// k2m: fallback if ws too small for keys — round-1 passing kernel (+pad)
// ---------------------------------------------------------------------------
__global__ __launch_bounds__(NT, 2)
void vq_mono(const float* __restrict__ latent, const float* __restrict__ weight,
             const float* __restrict__ wnorm, float* __restrict__ out) {
  __shared__ __align__(16) float As[BD][64];
  __shared__ __align__(16) float Ws[BD][WSP];
  __shared__ int   sIdx[64];
  __shared__ float sRed[4];

  const int tid = threadIdx.x;
  const int blk = blockIdx.x;
  const int tx  = tid & 15;
  const int ty  = tid >> 4;
  const int b   = blk >> 4;
  const int hw0 = (blk & 15) * 64;
  const float* lat_b = latent + (size_t)b * DDIM * HWSZ;

  float xn[4] = {0.f, 0.f, 0.f, 0.f};
  for (int dc = 0; dc < DDIM / BD; ++dc) {
    __syncthreads();
#pragma unroll
    for (int i = 0; i < 2; ++i) {
      int idx = tid + i * NT;
      int dd = idx >> 4, f4 = idx & 15;
      *(float4*)&As[dd][f4 * 4] =
          *(const float4*)(lat_b + (size_t)(dc * BD + dd) * HWSZ + hw0 + f4 * 4);
    }
    __syncthreads();
#pragma unroll 8
    for (int dd = 0; dd < BD; ++dd) {
      float4 a = *(const float4*)&As[dd][ty * 4];
      xn[0] += a.x * a.x; xn[1] += a.y * a.y;
      xn[2] += a.z * a.z; xn[3] += a.w * a.w;
    }
  }

  float best[4] = {INFINITY, INFINITY, INFINITY, INFINITY};
  int   bidx[4] = {0, 0, 0, 0};

  for (int kt = 0; kt < KCODES / 128; ++kt) {
    const int k0 = kt * 128;
    float acc[4][8];
#pragma unroll
    for (int r = 0; r < 4; ++r)
#pragma unroll
      for (int c = 0; c < 8; ++c) acc[r][c] = 0.f;

    for (int dc = 0; dc < DDIM / BD; ++dc) {
      const int d0 = dc * BD;
      __syncthreads();
#pragma unroll
      for (int i = 0; i < 2; ++i) {
        int idx = tid + i * NT;
        int dd = idx >> 4, f4 = idx & 15;
        *(float4*)&As[dd][f4 * 4] =
            *(const float4*)(lat_b + (size_t)(d0 + dd) * HWSZ + hw0 + f4 * 4);
      }
#pragma unroll
      for (int i = 0; i < 4; ++i) {
        int idx = tid + i * NT;
        int kl = idx >> 3, df = idx & 7;
        float4 v = *(const float4*)(weight + (size_t)(k0 + kl) * DDIM + d0 + df * 4);
        Ws[df * 4 + 0][kl] = v.x;
        Ws[df * 4 + 1][kl] = v.y;
        Ws[df * 4 + 2][kl] = v.z;
        Ws[df * 4 + 3][kl] = v.w;
      }
      __syncthreads();

#pragma unroll 8
      for (int dd = 0; dd < BD; ++dd) {
        float4 a  = *(const float4*)&As[dd][ty * 4];
        float4 w0 = *(const float4*)&Ws[dd][tx * 4];
        float4 w1 = *(const float4*)&Ws[dd][64 + tx * 4];
        float av[4] = {a.x, a.y, a.z, a.w};
        float wv[8] = {w0.x, w0.y, w0.z, w0.w, w1.x, w1.y, w1.z, w1.w};
#pragma unroll
        for (int r = 0; r < 4; ++r)
#pragma unroll
          for (int c = 0; c < 8; ++c)
            acc[r][c] += av[r] * wv[c];
      }
    }

#pragma unroll
    for (int c = 0; c < 8; ++c) {
      const int kg = k0 + ((c < 4) ? (tx * 4 + c) : (64 + tx * 4 + (c - 4)));
      const float wn = wnorm[kg];
#pragma unroll
      for (int r = 0; r < 4; ++r) {
        float dist = (xn[r] + wn) - 2.0f * acc[r][c];
        if (dist < best[r] || (dist == best[r] && kg < bidx[r])) {
          best[r] = dist; bidx[r] = kg;
        }
      }
    }
  }

#pragma unroll
  for (int j = 0; j < 4; ++j) {
    float bd = best[j];
    int   bi = bidx[j];
#pragma unroll
    for (int off = 1; off < 16; off <<= 1) {
      float od = __shfl_xor(bd, off);
      int   oi = __shfl_xor(bi, off);
      if (od < bd || (od == bd && oi < bi)) { bd = od; bi = oi; }
    }
    if (tx == 0) sIdx[ty * 4 + j] = bi;
  }
  __syncthreads();

  const int hwl = tid & 63;
  const int wv  = tid >> 6;
  const int ksel = sIdx[hwl];
  const float* wrow = weight + (size_t)ksel * DDIM;
  float lsum = 0.f;
#pragma unroll 4
  for (int it = 0; it < 64; ++it) {
    int d = it * 4 + wv;
    size_t off = (size_t)d * HWSZ + hw0 + hwl;
    float x = lat_b[off];
    float qv = wrow[d];
    out[(size_t)b * DDIM * HWSZ + off] = qv;
    float df = qv - x;
    lsum += df * df;
  }
#pragma unroll
  for (int off = 1; off < 64; off <<= 1) lsum += __shfl_xor(lsum, off);
  if ((tid & 63) == 0) sRed[tid >> 6] = lsum;
  __syncthreads();
  if (tid == 0) {
    float t = sRed[0] + sRed[1] + sRed[2] + sRed[3];
    atomicAdd(out + (size_t)NROWS * DDIM, t * (1.0f / ((float)NROWS * (float)DDIM)));
  }
}

// ---------------------------------------------------------------------------
extern "C" void kernel_launch(void* const* d_in, const int* in_sizes, int n_in,
                              void* d_out, int out_size, void* d_ws, size_t ws_size,
                              hipStream_t stream) {
  const float* latent = (const float*)d_in[0];   // (32,256,32,32) f32
  const float* weight = (const float*)d_in[1];   // (1024,256)     f32
  float* out   = (float*)d_out;                  // 8388608 + 1 (loss)
  char*  ws    = (char*)d_ws;
  float* wnorm = (float*)(ws + WS_WNORM);

  vq_wnorm<<<KCODES / 4, 256, 0, stream>>>(weight, wnorm, out + (size_t)NROWS * DDIM);

  if (ws_size >= (size_t)WS_NEED) {
    unsigned long long* keys = (unsigned long long*)(ws + WS_KEYS);
    hipMemsetAsync(ws + WS_KEYS, 0xFF, (size_t)NROWS * 8, stream);
    vq_dist<<<1024, NT, 0, stream>>>(latent, weight, wnorm, keys);
    vq_emit<<< 512, 256, 0, stream>>>(latent, weight, keys, out);
  } else {
    vq_mono<<< 512, NT, 0, stream>>>(latent, weight, wnorm, out);
  }
}

// Round 8
// 303.507 us; speedup vs baseline: 1.0521x; 1.0521x over previous
//
#include <hip/hip_runtime.h>
#include <math.h>
#include <stdint.h>

#define DDIM   256
#define HWSZ   1024
#define NROWS  32768
#define KCODES 1024
#define BN     64
#define BK     128
#define BD     32
#define NT     256
#define WSP    132

// ws layout: [0,4096) f32 wnorm[1024]; [4096, 4096+262144) u64 keys[32768]
#define WS_WNORM 0
#define WS_KEYS  4096
#define WS_NEED  (4096 + NROWS * 8)

__device__ __forceinline__ uint32_t fbits(float f) { return __float_as_uint(f); }

// ---------------------------------------------------------------------------
// k1: per-code squared norms + zero the loss slot (proven, verbatim)
// ---------------------------------------------------------------------------
__global__ __launch_bounds__(256)
void vq_wnorm(const float* __restrict__ weight, float* __restrict__ wnorm,
              float* __restrict__ loss_slot) {
  const int tid  = threadIdx.x;
  const int lane = tid & 63;
  const int code = blockIdx.x * 4 + (tid >> 6);
  float4 v = *(const float4*)(weight + (size_t)code * DDIM + lane * 4);
  float s = v.x * v.x + v.y * v.y + v.z * v.z + v.w * v.w;
#pragma unroll
  for (int off = 1; off < 64; off <<= 1) s += __shfl_xor(s, off);
  if (lane == 0) wnorm[code] = s;
  if (blockIdx.x == 0 && tid == 0) *loss_slot = 0.0f;
}

// ---------------------------------------------------------------------------
// k2: ROUND-6 PROVEN KERNEL + two surgical changes:
//   (a) xn folded into kt=0 compute loop (same dc/dd order -> bit-identical)
//   (b) Ws staging swizzle phys = code ^ (row & 24) (round-7 validated,
//       removes the 4-way quarter-wave write conflict; reads stay 2-way)
// Block = 64 rows x 256 codes (quarter q = bid & 3, round-6 locality).
// ---------------------------------------------------------------------------
__global__ __launch_bounds__(NT, 4)
void vq_dist(const float* __restrict__ latent, const float* __restrict__ weight,
             const float* __restrict__ wnorm,
             unsigned long long* __restrict__ keys) {
  __shared__ __align__(16) float As[BD][BN];    // 8 KB
  __shared__ __align__(16) float Ws[BD][WSP];   // 16.9 KB

  const int tid = threadIdx.x;
  const int tx  = tid & 15;            // code group: 16 groups x 8 codes
  const int ty  = tid >> 4;            // row group : 16 groups x 4 rows
  const int rb  = blockIdx.x >> 2;     // row-block 0..511 (64 rows each)
  const int q   = blockIdx.x & 3;      // code quarter 0..3 (adjacent siblings)
  const int b   = rb >> 4;
  const int hw0 = (rb & 15) * BN;
  const float* lat_b = latent + (size_t)b * DDIM * HWSZ;

  float xn[4] = {0.f, 0.f, 0.f, 0.f};
  float best[4] = {INFINITY, INFINITY, INFINITY, INFINITY};
  int   bidx[4] = {0, 0, 0, 0};

#pragma unroll
  for (int kt = 0; kt < 2; ++kt) {
    const int k0 = q * 256 + kt * BK;
    float acc[4][8];
#pragma unroll
    for (int r = 0; r < 4; ++r)
#pragma unroll
      for (int c = 0; c < 8; ++c) acc[r][c] = 0.f;

    for (int dc = 0; dc < DDIM / BD; ++dc) {
      const int d0 = dc * BD;
      __syncthreads();
      // stage A chunk: 32 d x 64 rows (conflict-free per quarter-phase)
#pragma unroll
      for (int i = 0; i < 2; ++i) {
        int idx = tid + i * NT;
        int dd = idx >> 4, f4 = idx & 15;
        *(float4*)&As[dd][f4 * 4] =
            *(const float4*)(lat_b + (size_t)(d0 + dd) * HWSZ + hw0 + f4 * 4);
      }
      // stage W chunk transposed, swizzled: phys = code ^ (row & 24)
#pragma unroll
      for (int i = 0; i < 4; ++i) {
        int idx = tid + i * NT;
        int kl = idx >> 3, df = idx & 7;
        float4 v = *(const float4*)(weight + (size_t)(k0 + kl) * DDIM + d0 + df * 4);
        const int swz = kl ^ ((df >> 1) << 3);   // rows df*4+j share row&24 = (df>>1)<<3
        Ws[df * 4 + 0][swz] = v.x;
        Ws[df * 4 + 1][swz] = v.y;
        Ws[df * 4 + 2][swz] = v.z;
        Ws[df * 4 + 3][swz] = v.w;
      }
      __syncthreads();

#pragma unroll 8
      for (int dd = 0; dd < BD; ++dd) {
        const int g8 = dd & 24;                  // read-side unswizzle
        float4 a  = *(const float4*)&As[dd][ty * 4];
        float4 w0 = *(const float4*)&Ws[dd][(tx * 4) ^ g8];
        float4 w1 = *(const float4*)&Ws[dd][64 + ((tx * 4) ^ g8)];
        if (kt == 0) {                           // xn: same dc/dd ascending order
          xn[0] += a.x * a.x; xn[1] += a.y * a.y;
          xn[2] += a.z * a.z; xn[3] += a.w * a.w;
        }
        float av[4] = {a.x, a.y, a.z, a.w};
        float wv[8] = {w0.x, w0.y, w0.z, w0.w, w1.x, w1.y, w1.z, w1.w};
#pragma unroll
        for (int r = 0; r < 4; ++r)
#pragma unroll
          for (int c = 0; c < 8; ++c)
            acc[r][c] += av[r] * wv[c];
      }
    }

    // distances on the reference's coarse grid (proven expression verbatim)
#pragma unroll
    for (int c = 0; c < 8; ++c) {
      const int kg = k0 + ((c < 4) ? (tx * 4 + c) : (64 + tx * 4 + (c - 4)));
      const float wn = wnorm[kg];
#pragma unroll
      for (int r = 0; r < 4; ++r) {
        float dist = (xn[r] + wn) - 2.0f * acc[r][c];
        if (dist < best[r] || (dist == best[r] && kg < bidx[r])) {
          best[r] = dist; bidx[r] = kg;
        }
      }
    }
  }

  // reduce argmin across the 16 code-threads per row; global fold via atomicMin
#pragma unroll
  for (int j = 0; j < 4; ++j) {
    float bd = best[j];
    int   bi = bidx[j];
#pragma unroll
    for (int off = 1; off < 16; off <<= 1) {
      float od = __shfl_xor(bd, off);
      int   oi = __shfl_xor(bi, off);
      if (od < bd || (od == bd && oi < bi)) { bd = od; bi = oi; }
    }
    if (tx == 0) {
      uint32_t db   = fbits(bd);
      uint32_t flip = (db & 0x80000000u) ? ~db : (db | 0x80000000u);
      unsigned long long key =
          ((unsigned long long)flip << 32) | (unsigned long long)(uint32_t)bi;
      atomicMin(&keys[rb * 64 + ty * 4 + j], key);
    }
  }
}

// ---------------------------------------------------------------------------
// k3: keys -> idx, gather codes, transposed coalesced output, loss (proven)
// ---------------------------------------------------------------------------
__global__ __launch_bounds__(256)
void vq_emit(const float* __restrict__ latent, const float* __restrict__ weight,
             const unsigned long long* __restrict__ keys, float* __restrict__ out) {
  __shared__ int   sIdx[64];
  __shared__ float sRed[4];
  const int t   = threadIdx.x;
  const int blk = blockIdx.x;
  const int b   = blk >> 4;
  const int hw0 = (blk & 15) * 64;
  if (t < 64) sIdx[t] = (int)(keys[blk * 64 + t] & 0x3FFull);
  __syncthreads();

  const int hw4  = (t & 15) * 4;
  const int dgrp = t >> 4;
  const float* lat_b = latent + (size_t)b * DDIM * HWSZ;
  float* out_b = out + (size_t)b * DDIM * HWSZ;
  const float* w0 = weight + (size_t)sIdx[hw4 + 0] * DDIM;
  const float* w1 = weight + (size_t)sIdx[hw4 + 1] * DDIM;
  const float* w2 = weight + (size_t)sIdx[hw4 + 2] * DDIM;
  const float* w3 = weight + (size_t)sIdx[hw4 + 3] * DDIM;
  float lsum = 0.f;
#pragma unroll
  for (int it = 0; it < 16; ++it) {
    const int d = it * 16 + dgrp;
    float4 xv = *(const float4*)(lat_b + (size_t)d * HWSZ + hw0 + hw4);
    float q0 = w0[d], q1 = w1[d], q2 = w2[d], q3 = w3[d];
    *(float4*)(out_b + (size_t)d * HWSZ + hw0 + hw4) = make_float4(q0, q1, q2, q3);
    float e0 = q0 - xv.x, e1 = q1 - xv.y, e2 = q2 - xv.z, e3 = q3 - xv.w;
    lsum += e0 * e0 + e1 * e1 + e2 * e2 + e3 * e3;
  }
#pragma unroll
  for (int s = 1; s < 64; s <<= 1) lsum += __shfl_xor(lsum, s);
  if ((t & 63) == 0) sRed[t >> 6] = lsum;
  __syncthreads();
  if (t == 0) {
    float tot = sRed[0] + sRed[1] + sRed[2] + sRed[3];
    atomicAdd(out + (size_t)NROWS * DDIM, tot * (1.0f / 8388608.0f));
  }
}

// ---------------------------------------------------------------------------
// k2m: fallback if ws too small for keys — round-1 passing kernel (+pad)
// ---------------------------------------------------------------------------
__global__ __launch_bounds__(NT, 2)
void vq_mono(const float* __restrict__ latent, const float* __restrict__ weight,
             const float* __restrict__ wnorm, float* __restrict__ out) {
  __shared__ __align__(16) float As[BD][BN];
  __shared__ __align__(16) float Ws[BD][WSP];
  __shared__ int   sIdx[BN];
  __shared__ float sRed[4];

  const int tid = threadIdx.x;
  const int blk = blockIdx.x;
  const int tx  = tid & 15;
  const int ty  = tid >> 4;
  const int b   = blk >> 4;
  const int hw0 = (blk & 15) * BN;
  const float* lat_b = latent + (size_t)b * DDIM * HWSZ;

  float xn[4] = {0.f, 0.f, 0.f, 0.f};
  for (int dc = 0; dc < DDIM / BD; ++dc) {
    __syncthreads();
#pragma unroll
    for (int i = 0; i < 2; ++i) {
      int idx = tid + i * NT;
      int dd = idx >> 4, f4 = idx & 15;
      *(float4*)&As[dd][f4 * 4] =
          *(const float4*)(lat_b + (size_t)(dc * BD + dd) * HWSZ + hw0 + f4 * 4);
    }
    __syncthreads();
#pragma unroll 8
    for (int dd = 0; dd < BD; ++dd) {
      float4 a = *(const float4*)&As[dd][ty * 4];
      xn[0] += a.x * a.x; xn[1] += a.y * a.y;
      xn[2] += a.z * a.z; xn[3] += a.w * a.w;
    }
  }

  float best[4] = {INFINITY, INFINITY, INFINITY, INFINITY};
  int   bidx[4] = {0, 0, 0, 0};

  for (int kt = 0; kt < KCODES / BK; ++kt) {
    const int k0 = kt * BK;
    float acc[4][8];
#pragma unroll
    for (int r = 0; r < 4; ++r)
#pragma unroll
      for (int c = 0; c < 8; ++c) acc[r][c] = 0.f;

    for (int dc = 0; dc < DDIM / BD; ++dc) {
      const int d0 = dc * BD;
      __syncthreads();
#pragma unroll
      for (int i = 0; i < 2; ++i) {
        int idx = tid + i * NT;
        int dd = idx >> 4, f4 = idx & 15;
        *(float4*)&As[dd][f4 * 4] =
            *(const float4*)(lat_b + (size_t)(d0 + dd) * HWSZ + hw0 + f4 * 4);
      }
#pragma unroll
      for (int i = 0; i < 4; ++i) {
        int idx = tid + i * NT;
        int kl = idx >> 3, df = idx & 7;
        float4 v = *(const float4*)(weight + (size_t)(k0 + kl) * DDIM + d0 + df * 4);
        Ws[df * 4 + 0][kl] = v.x;
        Ws[df * 4 + 1][kl] = v.y;
        Ws[df * 4 + 2][kl] = v.z;
        Ws[df * 4 + 3][kl] = v.w;
      }
      __syncthreads();

#pragma unroll 8
      for (int dd = 0; dd < BD; ++dd) {
        float4 a  = *(const float4*)&As[dd][ty * 4];
        float4 w0 = *(const float4*)&Ws[dd][tx * 4];
        float4 w1 = *(const float4*)&Ws[dd][64 + tx * 4];
        float av[4] = {a.x, a.y, a.z, a.w};
        float wv[8] = {w0.x, w0.y, w0.z, w0.w, w1.x, w1.y, w1.z, w1.w};
#pragma unroll
        for (int r = 0; r < 4; ++r)
#pragma unroll
          for (int c = 0; c < 8; ++c)
            acc[r][c] += av[r] * wv[c];
      }
    }

#pragma unroll
    for (int c = 0; c < 8; ++c) {
      const int kg = k0 + ((c < 4) ? (tx * 4 + c) : (64 + tx * 4 + (c - 4)));
      const float wn = wnorm[kg];
#pragma unroll
      for (int r = 0; r < 4; ++r) {
        float dist = (xn[r] + wn) - 2.0f * acc[r][c];
        if (dist < best[r] || (dist == best[r] && kg < bidx[r])) {
          best[r] = dist; bidx[r] = kg;
        }
      }
    }
  }

#pragma unroll
  for (int j = 0; j < 4; ++j) {
    float bd = best[j];
    int   bi = bidx[j];
#pragma unroll
    for (int off = 1; off < 16; off <<= 1) {
      float od = __shfl_xor(bd, off);
      int   oi = __shfl_xor(bi, off);
      if (od < bd || (od == bd && oi < bi)) { bd = od; bi = oi; }
    }
    if (tx == 0) sIdx[ty * 4 + j] = bi;
  }
  __syncthreads();

  const int hwl = tid & 63;
  const int wv  = tid >> 6;
  const int ksel = sIdx[hwl];
  const float* wrow = weight + (size_t)ksel * DDIM;
  float lsum = 0.f;
#pragma unroll 4
  for (int it = 0; it < 64; ++it) {
    int d = it * 4 + wv;
    size_t off = (size_t)d * HWSZ + hw0 + hwl;
    float x = lat_b[off];
    float qv = wrow[d];
    out[(size_t)b * DDIM * HWSZ + off] = qv;
    float df = qv - x;
    lsum += df * df;
  }
#pragma unroll
  for (int off = 1; off < 64; off <<= 1) lsum += __shfl_xor(lsum, off);
  if ((tid & 63) == 0) sRed[tid >> 6] = lsum;
  __syncthreads();
  if (tid == 0) {
    float t = sRed[0] + sRed[1] + sRed[2] + sRed[3];
    atomicAdd(out + (size_t)NROWS * DDIM, t * (1.0f / ((float)NROWS * (float)DDIM)));
  }
}

// ---------------------------------------------------------------------------
extern "C" void kernel_launch(void* const* d_in, const int* in_sizes, int n_in,
                              void* d_out, int out_size, void* d_ws, size_t ws_size,
                              hipStream_t stream) {
  const float* latent = (const float*)d_in[0];   // (32,256,32,32) f32
  const float* weight = (const float*)d_in[1];   // (1024,256)     f32
  float* out   = (float*)d_out;                  // 8388608 + 1 (loss)
  char*  ws    = (char*)d_ws;
  float* wnorm = (float*)(ws + WS_WNORM);

  vq_wnorm<<<KCODES / 4, 256, 0, stream>>>(weight, wnorm, out + (size_t)NROWS * DDIM);

  if (ws_size >= (size_t)WS_NEED) {
    unsigned long long* keys = (unsigned long long*)(ws + WS_KEYS);
    hipMemsetAsync(ws + WS_KEYS, 0xFF, (size_t)NROWS * 8, stream);
    vq_dist<<<2048, NT, 0, stream>>>(latent, weight, wnorm, keys);
    vq_emit<<< 512, 256, 0, stream>>>(latent, weight, keys, out);
  } else {
    vq_mono<<< 512, NT, 0, stream>>>(latent, weight, wnorm, out);
  }
}

// Round 9
// 225.959 us; speedup vs baseline: 1.4131x; 1.3432x over previous
//
#include <hip/hip_runtime.h>
#include <math.h>
#include <stdint.h>

#define DDIM   256
#define HWSZ   1024
#define NROWS  32768
#define KCODES 1024
#define BN     64
#define BK     128
#define BD     32
#define NT     256
#define WSP    132
#define TAU    4.0e-4f      // flag gap threshold (approx err ~1e-4 worst + grid 3e-5)
#define VEPS   2.0e-3f      // verify threshold (genuine err <=1.5e-4, layout err O(0.1))

// ws layout (byte offsets)
#define WS_WNORM 0                       // float[1024]           (4 KB)
#define WS_KEYS  4096                    // u64[32768]            (256 KB)
#define WS_FLAGS 266240                  // int[32768]            (128 KB)
#define WS_WHI   397312                  // bf16 hi tiles         (512 KB)
#define WS_WLO   921600                  // bf16 lo tiles         (512 KB)
#define WS_NEED_MFMA 1445888
#define WS_NEED_F32  266240

typedef __attribute__((ext_vector_type(8)))  short short8;
typedef __attribute__((ext_vector_type(16))) float f32x16;

__device__ __forceinline__ uint32_t fbits(float f) { return __float_as_uint(f); }
__device__ __forceinline__ float    ubits(uint32_t u) { return __uint_as_float(u); }
__device__ __forceinline__ uint32_t bf16rne(float f) {
  uint32_t u = fbits(f);
  return (u + 0x7FFFu + ((u >> 16) & 1u)) >> 16;
}
__device__ __forceinline__ uint32_t flipbits(float d) {
  uint32_t b = fbits(d);
  return (b & 0x80000000u) ? ~b : (b | 0x80000000u);
}
__device__ __forceinline__ float unflip(uint32_t x) {
  return ubits((x & 0x80000000u) ? (x & 0x7FFFFFFFu) : ~x);
}
__device__ __forceinline__ unsigned long long umin64(unsigned long long a, unsigned long long b) { return a < b ? a : b; }
__device__ __forceinline__ unsigned long long umax64(unsigned long long a, unsigned long long b) { return a > b ? a : b; }

// ---------------------------------------------------------------------------
// k1: per-code squared norms + zero the loss slot (proven, verbatim)
// ---------------------------------------------------------------------------
__global__ __launch_bounds__(256)
void vq_wnorm(const float* __restrict__ weight, float* __restrict__ wnorm,
              float* __restrict__ loss_slot) {
  const int tid  = threadIdx.x;
  const int lane = tid & 63;
  const int code = blockIdx.x * 4 + (tid >> 6);
  float4 v = *(const float4*)(weight + (size_t)code * DDIM + lane * 4);
  float s = v.x * v.x + v.y * v.y + v.z * v.z + v.w * v.w;
#pragma unroll
  for (int off = 1; off < 64; off <<= 1) s += __shfl_xor(s, off);
  if (lane == 0) wnorm[code] = s;
  if (blockIdx.x == 0 && tid == 0) *loss_slot = 0.0f;
}

// ---------------------------------------------------------------------------
// k1b: codebook -> bf16 hi/lo MFMA tiles in ws.
// Plane layout per 16-dim chunk: [2 k-octet][1024 code][8 bf16] (16B/lane).
// ---------------------------------------------------------------------------
__global__ __launch_bounds__(256)
void vq_prep(const float* __restrict__ weight, char* __restrict__ ws) {
  const int t    = threadIdx.x;
  const int code = blockIdx.x * 8 + (t >> 5);
  const int l32  = t & 31;
  const int d0   = l32 * 8;
  const int ch   = l32 >> 1;
  const int slot = l32 & 1;
  const float* wr = weight + (size_t)code * DDIM + d0;
  float4 f0 = *(const float4*)(wr);
  float4 f1 = *(const float4*)(wr + 4);
  float x[8] = {f0.x, f0.y, f0.z, f0.w, f1.x, f1.y, f1.z, f1.w};
  uint32_t hp[4], lp[4];
#pragma unroll
  for (int j = 0; j < 4; ++j) {
    float a = x[2*j], b = x[2*j+1];
    uint32_t ha = bf16rne(a), hb = bf16rne(b);
    float la = a - ubits(ha << 16), lb = b - ubits(hb << 16);
    hp[j] = ha | (bf16rne(b) << 16);
    // recompute hb-based lo exactly:
    lb = b - ubits(hb << 16);
    lp[j] = bf16rne(la) | (bf16rne(lb) << 16);
  }
  const size_t off = (size_t)ch * 32768 + (size_t)slot * 16384 + (size_t)code * 16;
  *(uint4*)(ws + WS_WHI + off) = make_uint4(hp[0], hp[1], hp[2], hp[3]);
  *(uint4*)(ws + WS_WLO + off) = make_uint4(lp[0], lp[1], lp[2], lp[3]);
}

// ---------------------------------------------------------------------------
// k2: split-bf16 4-term MFMA argmin. Block = 32 rows x 1024 codes, 8 waves.
// Wave = 32 rows x 128 codes. Self-verifying: every row's winning distance is
// re-checked exactly; any mismatch flags the whole block for coarse fixup.
// ---------------------------------------------------------------------------
__global__ __launch_bounds__(512, 2)
void vq_mfma(const float* __restrict__ latent, const float* __restrict__ weight,
             char* __restrict__ ws) {
  __shared__ __align__(16) short AH[2][32][8];      // 1 KB  [oct][row][8]
  __shared__ __align__(16) short AL[2][32][8];      // 1 KB
  __shared__ __align__(16) short WH[2][1024][8];    // 32 KB [oct][code][8]
  __shared__ ulonglong2 cand[32][8][4];             // 16 KB
  __shared__ unsigned long long sM1[32];
  __shared__ int sGap[32];
  __shared__ int sVer[8];

  const int tid  = threadIdx.x;
  const int l    = tid & 63;
  const int w    = tid >> 6;
  const int ln31 = l & 31;
  const int half = l >> 5;
  const int b    = blockIdx.x >> 5;
  const int hw0  = (blockIdx.x & 31) * 32;
  const float* lat_b = latent + (size_t)b * (DDIM * HWSZ);
  const char* whi = ws + WS_WHI;
  const char* wlo = ws + WS_WLO;
  const float* wnorm = (const float*)(ws + WS_WNORM);

  f32x16 acc[4];
#pragma unroll
  for (int cg = 0; cg < 4; ++cg) acc[cg] = (f32x16)0.0f;

  const int arow = tid & 31;      // A-convert assignment: 32 rows x 16 dims
  const int adim = tid >> 5;

  for (int ch = 0; ch < 16; ++ch) {
    __syncthreads();   // protect previous chunk's reads
    // ---- stage A: convert 1 latent value/thread to bf16 hi/lo ----
    {
      float x = lat_b[(size_t)(ch * 16 + adim) * HWSZ + hw0 + arow];
      uint32_t h = bf16rne(x);
      float lo = x - ubits(h << 16);
      AH[adim >> 3][arow][adim & 7] = (short)h;
      AL[adim >> 3][arow][adim & 7] = (short)bf16rne(lo);
    }
    // ---- stage WH plane (32 KB) via global_load_lds ----
#pragma unroll
    for (int i = 0; i < 4; ++i) {
      const int o = (w * 4 + i) * 1024;
      __builtin_amdgcn_global_load_lds(
          (const __attribute__((address_space(1))) uint32_t*)(whi + (size_t)ch * 32768 + o + l * 16),
          (__attribute__((address_space(3))) uint32_t*)(((char*)WH) + o),
          16, 0, 0);
    }
    __syncthreads();   // A visible + WH loaded (barrier drains vmcnt)

    short8 ah = *(const short8*)&AH[half][ln31][0];
    short8 al = *(const short8*)&AL[half][ln31][0];
#pragma unroll
    for (int cg = 0; cg < 4; ++cg) {
      const int code = w * 128 + cg * 32 + ln31;
      short8 bh = *(const short8*)&WH[half][code][0];
      short8 bl = *(const short8*)(wlo + (size_t)ch * 32768 + (size_t)half * 16384 + (size_t)code * 16);
      acc[cg] = __builtin_amdgcn_mfma_f32_32x32x16_bf16(ah, bh, acc[cg], 0, 0, 0);
      acc[cg] = __builtin_amdgcn_mfma_f32_32x32x16_bf16(al, bh, acc[cg], 0, 0, 0);
      acc[cg] = __builtin_amdgcn_mfma_f32_32x32x16_bf16(ah, bl, acc[cg], 0, 0, 0);
      acc[cg] = __builtin_amdgcn_mfma_f32_32x32x16_bf16(al, bl, acc[cg], 0, 0, 0);
    }
  }

  // ---- fold: per-row best/second-best over this wave's 128 codes ----
  float wnv[4];
#pragma unroll
  for (int cg = 0; cg < 4; ++cg) wnv[cg] = wnorm[w * 128 + cg * 32 + ln31];

#pragma unroll
  for (int reg = 0; reg < 16; ++reg) {
    unsigned long long kk[4];
#pragma unroll
    for (int cg = 0; cg < 4; ++cg) {
      const int code = w * 128 + cg * 32 + ln31;
      float dk = fmaf(-2.0f, acc[cg][reg], wnv[cg]);   // xn dropped: gap-based flagging
      kk[cg] = (((unsigned long long)flipbits(dk)) << 32) | (unsigned long long)(uint32_t)code;
    }
    unsigned long long a = umin64(kk[0], kk[1]), bb = umax64(kk[0], kk[1]);
    unsigned long long c = umin64(kk[2], kk[3]), e  = umax64(kk[2], kk[3]);
    unsigned long long m1 = umin64(a, c);
    unsigned long long m2 = umin64(umin64(bb, e), umax64(a, c));
#pragma unroll
    for (int s = 1; s <= 4; s <<= 1) {
      unsigned long long om1 = __shfl_xor(m1, s);
      unsigned long long om2 = __shfl_xor(m2, s);
      unsigned long long nm2 = umin64(umin64(m2, om2), umax64(m1, om1));
      m1 = umin64(m1, om1);
      m2 = nm2;
    }
    if ((l & 7) == 0) {
      const int row = (reg & 3) + 8 * (reg >> 2) + 4 * half;   // verified C/D map
      cand[row][w][ln31 >> 3] = make_ulonglong2(m1, m2);
    }
  }
  __syncthreads();

  // ---- merge across waves; emit keys + gap flags ----
  unsigned long long* keys = (unsigned long long*)(ws + WS_KEYS);
  if (tid < 128) {
    const int row = tid >> 2, q = tid & 3;
    unsigned long long m1 = 0xFFFFFFFFFFFFFFFFull, m2 = 0xFFFFFFFFFFFFFFFFull;
#pragma unroll
    for (int ww = 0; ww < 8; ++ww) {
      ulonglong2 cc = cand[row][ww][q];
      unsigned long long nm2 = umin64(umin64(m2, cc.y), umax64(m1, cc.x));
      m1 = umin64(m1, cc.x);
      m2 = nm2;
    }
#pragma unroll
    for (int s = 1; s <= 2; s <<= 1) {
      unsigned long long om1 = __shfl_xor(m1, s);
      unsigned long long om2 = __shfl_xor(m2, s);
      unsigned long long nm2 = umin64(umin64(m2, om2), umax64(m1, om1));
      m1 = umin64(m1, om1);
      m2 = nm2;
    }
    if (q == 0) {
      atomicMin(&keys[blockIdx.x * 32 + row], m1);
      float d1 = unflip((uint32_t)(m1 >> 32));
      float d2 = unflip((uint32_t)(m2 >> 32));
      sGap[row] = (d2 - d1 < TAU) ? 1 : 0;
      sM1[row]  = m1;
    }
  }
  __syncthreads();

  // ---- verify all 32 rows: exact f32 check of each claimed winner ----
  {
    int bad = 0;
#pragma unroll
    for (int i = 0; i < 4; ++i) {
      const int row = w * 4 + i;
      unsigned long long m1 = sM1[row];
      const int c = (int)(m1 & 0x3FFull);
      float d1 = unflip((uint32_t)(m1 >> 32));
      float4 wv = *(const float4*)(weight + (size_t)c * DDIM + l * 4);
      float x0 = lat_b[(size_t)(4 * l + 0) * HWSZ + hw0 + row];
      float x1 = lat_b[(size_t)(4 * l + 1) * HWSZ + hw0 + row];
      float x2 = lat_b[(size_t)(4 * l + 2) * HWSZ + hw0 + row];
      float x3 = lat_b[(size_t)(4 * l + 3) * HWSZ + hw0 + row];
      float p = x0 * wv.x + x1 * wv.y + x2 * wv.z + x3 * wv.w;
#pragma unroll
      for (int s = 1; s < 64; s <<= 1) p += __shfl_xor(p, s);
      float dex = wnorm[c] - 2.0f * p;
      bad |= (fabsf(dex - d1) > VEPS) ? 1 : 0;
    }
    if (l == 0) sVer[w] = bad;
  }
  __syncthreads();
  if (tid == 0) {
    int vb = 0;
#pragma unroll
    for (int i = 0; i < 8; ++i) vb |= sVer[i];
    sVer[0] = vb;
  }
  __syncthreads();
  if (tid < 32) {
    ((int*)(ws + WS_FLAGS))[blockIdx.x * 32 + tid] = sGap[tid] | sVer[0];
  }
}

// ---------------------------------------------------------------------------
// k2b: exact coarse-grid re-argmin for flagged rows (round-6 math verbatim:
// sequential xn, dist = (xn + wn) - 2*dot, lowest-index ties). Overwrites keys.
// ---------------------------------------------------------------------------
__global__ __launch_bounds__(256)
void vq_fixc(const float* __restrict__ latent, const float* __restrict__ weight,
             char* __restrict__ ws) {
  __shared__ float xs[256];
  __shared__ float bd[4];
  __shared__ int   bix[4];
  const int t = threadIdx.x;
  const int* flags = (const int*)(ws + WS_FLAGS);
  const float* wnorm = (const float*)(ws + WS_WNORM);
  unsigned long long* keys = (unsigned long long*)(ws + WS_KEYS);

  for (int rloc = 0; rloc < 64; ++rloc) {
    const int grow = blockIdx.x * 64 + rloc;
    if (!flags[grow]) continue;                      // uniform per block
    const int b = grow >> 10, hw = grow & 1023;
    __syncthreads();
    xs[t] = latent[(size_t)b * (DDIM * HWSZ) + (size_t)t * HWSZ + hw];
    __syncthreads();
    // sequential xn (round-6 order: dims ascending, element by element)
    float xnv = 0.f;
    const float4* x4 = (const float4*)xs;
#pragma unroll 16
    for (int k = 0; k < 64; ++k) {
      float4 xq = x4[k];
      xnv += xq.x * xq.x; xnv += xq.y * xq.y;
      xnv += xq.z * xq.z; xnv += xq.w * xq.w;
    }
    float best = INFINITY; int bi = 0;
    for (int j = 0; j < 4; ++j) {
      const int c = 256 * j + t;
      const float4* w4 = (const float4*)(weight + (size_t)c * DDIM);
      float dot = 0.f;
#pragma unroll 16
      for (int k = 0; k < 64; ++k) {
        float4 wv = w4[k];
        dot = fmaf(xs[4*k  ], wv.x, dot);
        dot = fmaf(xs[4*k+1], wv.y, dot);
        dot = fmaf(xs[4*k+2], wv.z, dot);
        dot = fmaf(xs[4*k+3], wv.w, dot);
      }
      float dist = (xnv + wnorm[c]) - 2.0f * dot;    // coarse grid, verbatim
      if (dist < best || (dist == best && c < bi)) { best = dist; bi = c; }
    }
#pragma unroll
    for (int s = 1; s <= 32; s <<= 1) {
      float od = __shfl_xor(best, s);
      int   oi = __shfl_xor(bi, s);
      if (od < best || (od == best && oi < bi)) { best = od; bi = oi; }
    }
    if ((t & 63) == 0) { bd[t >> 6] = best; bix[t >> 6] = bi; }
    __syncthreads();
    if (t == 0) {
      float fb = bd[0]; int fbi = bix[0];
#pragma unroll
      for (int ww = 1; ww < 4; ++ww)
        if (bd[ww] < fb || (bd[ww] == fb && bix[ww] < fbi)) { fb = bd[ww]; fbi = bix[ww]; }
      keys[grow] = (((unsigned long long)flipbits(fb)) << 32) | (unsigned long long)(uint32_t)fbi;
    }
    __syncthreads();
  }
}

// ---------------------------------------------------------------------------
// k3: keys -> idx, gather codes, transposed coalesced output, loss (proven)
// ---------------------------------------------------------------------------
__global__ __launch_bounds__(256)
void vq_emit(const float* __restrict__ latent, const float* __restrict__ weight,
             const unsigned long long* __restrict__ keys, float* __restrict__ out) {
  __shared__ int   sIdx[64];
  __shared__ float sRed[4];
  const int t   = threadIdx.x;
  const int blk = blockIdx.x;
  const int b   = blk >> 4;
  const int hw0 = (blk & 15) * 64;
  if (t < 64) sIdx[t] = (int)(keys[blk * 64 + t] & 0x3FFull);
  __syncthreads();

  const int hw4  = (t & 15) * 4;
  const int dgrp = t >> 4;
  const float* lat_b = latent + (size_t)b * DDIM * HWSZ;
  float* out_b = out + (size_t)b * DDIM * HWSZ;
  const float* w0 = weight + (size_t)sIdx[hw4 + 0] * DDIM;
  const float* w1 = weight + (size_t)sIdx[hw4 + 1] * DDIM;
  const float* w2 = weight + (size_t)sIdx[hw4 + 2] * DDIM;
  const float* w3 = weight + (size_t)sIdx[hw4 + 3] * DDIM;
  float lsum = 0.f;
#pragma unroll
  for (int it = 0; it < 16; ++it) {
    const int d = it * 16 + dgrp;
    float4 xv = *(const float4*)(lat_b + (size_t)d * HWSZ + hw0 + hw4);
    float q0 = w0[d], q1 = w1[d], q2 = w2[d], q3 = w3[d];
    *(float4*)(out_b + (size_t)d * HWSZ + hw0 + hw4) = make_float4(q0, q1, q2, q3);
    float e0 = q0 - xv.x, e1 = q1 - xv.y, e2 = q2 - xv.z, e3 = q3 - xv.w;
    lsum += e0 * e0 + e1 * e1 + e2 * e2 + e3 * e3;
  }
#pragma unroll
  for (int s = 1; s < 64; s <<= 1) lsum += __shfl_xor(lsum, s);
  if ((t & 63) == 0) sRed[t >> 6] = lsum;
  __syncthreads();
  if (t == 0) {
    float tot = sRed[0] + sRed[1] + sRed[2] + sRed[3];
    atomicAdd(out + (size_t)NROWS * DDIM, tot * (1.0f / 8388608.0f));
  }
}

// ---------------------------------------------------------------------------
// Fallback tier 1: round-6 proven f32 kernel (verbatim)
// ---------------------------------------------------------------------------
__global__ __launch_bounds__(NT, 4)
void vq_dist(const float* __restrict__ latent, const float* __restrict__ weight,
             const float* __restrict__ wnorm,
             unsigned long long* __restrict__ keys) {
  __shared__ __align__(16) float As[BD][BN];
  __shared__ __align__(16) float Ws[BD][WSP];

  const int tid = threadIdx.x;
  const int tx  = tid & 15;
  const int ty  = tid >> 4;
  const int rb  = blockIdx.x >> 2;
  const int q   = blockIdx.x & 3;
  const int b   = rb >> 4;
  const int hw0 = (rb & 15) * BN;
  const float* lat_b = latent + (size_t)b * DDIM * HWSZ;

  float xn[4] = {0.f, 0.f, 0.f, 0.f};
  for (int dc = 0; dc < DDIM / BD; ++dc) {
    __syncthreads();
#pragma unroll
    for (int i = 0; i < 2; ++i) {
      int idx = tid + i * NT;
      int dd = idx >> 4, f4 = idx & 15;
      *(float4*)&As[dd][f4 * 4] =
          *(const float4*)(lat_b + (size_t)(dc * BD + dd) * HWSZ + hw0 + f4 * 4);
    }
    __syncthreads();
#pragma unroll 8
    for (int dd = 0; dd < BD; ++dd) {
      float4 a = *(const float4*)&As[dd][ty * 4];
      xn[0] += a.x * a.x; xn[1] += a.y * a.y;
      xn[2] += a.z * a.z; xn[3] += a.w * a.w;
    }
  }

  float best[4] = {INFINITY, INFINITY, INFINITY, INFINITY};
  int   bidx[4] = {0, 0, 0, 0};

  for (int kt = 0; kt < 2; ++kt) {
    const int k0 = q * 256 + kt * BK;
    float acc[4][8];
#pragma unroll
    for (int r = 0; r < 4; ++r)
#pragma unroll
      for (int c = 0; c < 8; ++c) acc[r][c] = 0.f;

    for (int dc = 0; dc < DDIM / BD; ++dc) {
      const int d0 = dc * BD;
      __syncthreads();
#pragma unroll
      for (int i = 0; i < 2; ++i) {
        int idx = tid + i * NT;
        int dd = idx >> 4, f4 = idx & 15;
        *(float4*)&As[dd][f4 * 4] =
            *(const float4*)(lat_b + (size_t)(d0 + dd) * HWSZ + hw0 + f4 * 4);
      }
#pragma unroll
      for (int i = 0; i < 4; ++i) {
        int idx = tid + i * NT;
        int kl = idx >> 3, df = idx & 7;
        float4 v = *(const float4*)(weight + (size_t)(k0 + kl) * DDIM + d0 + df * 4);
        Ws[df * 4 + 0][kl] = v.x;
        Ws[df * 4 + 1][kl] = v.y;
        Ws[df * 4 + 2][kl] = v.z;
        Ws[df * 4 + 3][kl] = v.w;
      }
      __syncthreads();

#pragma unroll 8
      for (int dd = 0; dd < BD; ++dd) {
        float4 a  = *(const float4*)&As[dd][ty * 4];
        float4 w0 = *(const float4*)&Ws[dd][tx * 4];
        float4 w1 = *(const float4*)&Ws[dd][64 + tx * 4];
        float av[4] = {a.x, a.y, a.z, a.w};
        float wv[8] = {w0.x, w0.y, w0.z, w0.w, w1.x, w1.y, w1.z, w1.w};
#pragma unroll
        for (int r = 0; r < 4; ++r)
#pragma unroll
          for (int c = 0; c < 8; ++c)
            acc[r][c] += av[r] * wv[c];
      }
    }

#pragma unroll
    for (int c = 0; c < 8; ++c) {
      const int kg = k0 + ((c < 4) ? (tx * 4 + c) : (64 + tx * 4 + (c - 4)));
      const float wn = wnorm[kg];
#pragma unroll
      for (int r = 0; r < 4; ++r) {
        float dist = (xn[r] + wn) - 2.0f * acc[r][c];
        if (dist < best[r] || (dist == best[r] && kg < bidx[r])) {
          best[r] = dist; bidx[r] = kg;
        }
      }
    }
  }

#pragma unroll
  for (int j = 0; j < 4; ++j) {
    float bd = best[j];
    int   bi = bidx[j];
#pragma unroll
    for (int off = 1; off < 16; off <<= 1) {
      float od = __shfl_xor(bd, off);
      int   oi = __shfl_xor(bi, off);
      if (od < bd || (od == bd && oi < bi)) { bd = od; bi = oi; }
    }
    if (tx == 0) {
      unsigned long long key =
          (((unsigned long long)flipbits(bd)) << 32) | (unsigned long long)(uint32_t)bi;
      atomicMin(&keys[rb * 64 + ty * 4 + j], key);
    }
  }
}

// ---------------------------------------------------------------------------
// Fallback tier 2: mono (round-1 structure, proven semantics)
// ---------------------------------------------------------------------------
__global__ __launch_bounds__(NT, 2)
void vq_mono(const float* __restrict__ latent, const float* __restrict__ weight,
             const float* __restrict__ wnorm, float* __restrict__ out) {
  __shared__ __align__(16) float As[BD][BN];
  __shared__ __align__(16) float Ws[BD][WSP];
  __shared__ int   sIdx[BN];
  __shared__ float sRed[4];

  const int tid = threadIdx.x;
  const int blk = blockIdx.x;
  const int tx  = tid & 15;
  const int ty  = tid >> 4;
  const int b   = blk >> 4;
  const int hw0 = (blk & 15) * BN;
  const float* lat_b = latent + (size_t)b * DDIM * HWSZ;

  float xn[4] = {0.f, 0.f, 0.f, 0.f};
  for (int dc = 0; dc < DDIM / BD; ++dc) {
    __syncthreads();
#pragma unroll
    for (int i = 0; i < 2; ++i) {
      int idx = tid + i * NT;
      int dd = idx >> 4, f4 = idx & 15;
      *(float4*)&As[dd][f4 * 4] =
          *(const float4*)(lat_b + (size_t)(dc * BD + dd) * HWSZ + hw0 + f4 * 4);
    }
    __syncthreads();
#pragma unroll 8
    for (int dd = 0; dd < BD; ++dd) {
      float4 a = *(const float4*)&As[dd][ty * 4];
      xn[0] += a.x * a.x; xn[1] += a.y * a.y;
      xn[2] += a.z * a.z; xn[3] += a.w * a.w;
    }
  }

  float best[4] = {INFINITY, INFINITY, INFINITY, INFINITY};
  int   bidx[4] = {0, 0, 0, 0};

  for (int kt = 0; kt < KCODES / BK; ++kt) {
    const int k0 = kt * BK;
    float acc[4][8];
#pragma unroll
    for (int r = 0; r < 4; ++r)
#pragma unroll
      for (int c = 0; c < 8; ++c) acc[r][c] = 0.f;

    for (int dc = 0; dc < DDIM / BD; ++dc) {
      const int d0 = dc * BD;
      __syncthreads();
#pragma unroll
      for (int i = 0; i < 2; ++i) {
        int idx = tid + i * NT;
        int dd = idx >> 4, f4 = idx & 15;
        *(float4*)&As[dd][f4 * 4] =
            *(const float4*)(lat_b + (size_t)(d0 + dd) * HWSZ + hw0 + f4 * 4);
      }
#pragma unroll
      for (int i = 0; i < 4; ++i) {
        int idx = tid + i * NT;
        int kl = idx >> 3, df = idx & 7;
        float4 v = *(const float4*)(weight + (size_t)(k0 + kl) * DDIM + d0 + df * 4);
        Ws[df * 4 + 0][kl] = v.x;
        Ws[df * 4 + 1][kl] = v.y;
        Ws[df * 4 + 2][kl] = v.z;
        Ws[df * 4 + 3][kl] = v.w;
      }
      __syncthreads();

#pragma unroll 8
      for (int dd = 0; dd < BD; ++dd) {
        float4 a  = *(const float4*)&As[dd][ty * 4];
        float4 w0 = *(const float4*)&Ws[dd][tx * 4];
        float4 w1 = *(const float4*)&Ws[dd][64 + tx * 4];
        float av[4] = {a.x, a.y, a.z, a.w};
        float wv[8] = {w0.x, w0.y, w0.z, w0.w, w1.x, w1.y, w1.z, w1.w};
#pragma unroll
        for (int r = 0; r < 4; ++r)
#pragma unroll
          for (int c = 0; c < 8; ++c)
            acc[r][c] += av[r] * wv[c];
      }
    }

#pragma unroll
    for (int c = 0; c < 8; ++c) {
      const int kg = k0 + ((c < 4) ? (tx * 4 + c) : (64 + tx * 4 + (c - 4)));
      const float wn = wnorm[kg];
#pragma unroll
      for (int r = 0; r < 4; ++r) {
        float dist = (xn[r] + wn) - 2.0f * acc[r][c];
        if (dist < best[r] || (dist == best[r] && kg < bidx[r])) {
          best[r] = dist; bidx[r] = kg;
        }
      }
    }
  }

#pragma unroll
  for (int j = 0; j < 4; ++j) {
    float bd = best[j];
    int   bi = bidx[j];
#pragma unroll
    for (int off = 1; off < 16; off <<= 1) {
      float od = __shfl_xor(bd, off);
      int   oi = __shfl_xor(bi, off);
      if (od < bd || (od == bd && oi < bi)) { bd = od; bi = oi; }
    }
    if (tx == 0) sIdx[ty * 4 + j] = bi;
  }
  __syncthreads();

  const int hwl = tid & 63;
  const int wv  = tid >> 6;
  const int ksel = sIdx[hwl];
  const float* wrow = weight + (size_t)ksel * DDIM;
  float lsum = 0.f;
#pragma unroll 4
  for (int it = 0; it < 64; ++it) {
    int d = it * 4 + wv;
    size_t off = (size_t)d * HWSZ + hw0 + hwl;
    float x = lat_b[off];
    float qv = wrow[d];
    out[(size_t)b * DDIM * HWSZ + off] = qv;
    float df = qv - x;
    lsum += df * df;
  }
#pragma unroll
  for (int off = 1; off < 64; off <<= 1) lsum += __shfl_xor(lsum, off);
  if ((tid & 63) == 0) sRed[tid >> 6] = lsum;
  __syncthreads();
  if (tid == 0) {
    float t = sRed[0] + sRed[1] + sRed[2] + sRed[3];
    atomicAdd(out + (size_t)NROWS * DDIM, t * (1.0f / ((float)NROWS * (float)DDIM)));
  }
}

// ---------------------------------------------------------------------------
extern "C" void kernel_launch(void* const* d_in, const int* in_sizes, int n_in,
                              void* d_out, int out_size, void* d_ws, size_t ws_size,
                              hipStream_t stream) {
  const float* latent = (const float*)d_in[0];   // (32,256,32,32) f32
  const float* weight = (const float*)d_in[1];   // (1024,256)     f32
  float* out   = (float*)d_out;                  // 8388608 + 1 (loss)
  char*  ws    = (char*)d_ws;
  float* wnorm = (float*)(ws + WS_WNORM);

  vq_wnorm<<<KCODES / 4, 256, 0, stream>>>(weight, wnorm, out + (size_t)NROWS * DDIM);

  if (ws_size >= (size_t)WS_NEED_MFMA) {
    unsigned long long* keys = (unsigned long long*)(ws + WS_KEYS);
    hipMemsetAsync(ws + WS_KEYS,  0xFF, (size_t)NROWS * 8, stream);
    hipMemsetAsync(ws + WS_FLAGS, 0x00, (size_t)NROWS * 4, stream);
    vq_prep<<<KCODES / 8, 256, 0, stream>>>(weight, ws);
    vq_mfma<<<1024, 512, 0, stream>>>(latent, weight, ws);
    vq_fixc<<< 512, 256, 0, stream>>>(latent, weight, ws);
    vq_emit<<< 512, 256, 0, stream>>>(latent, weight, keys, out);
  } else if (ws_size >= (size_t)WS_NEED_F32) {
    unsigned long long* keys = (unsigned long long*)(ws + WS_KEYS);
    hipMemsetAsync(ws + WS_KEYS, 0xFF, (size_t)NROWS * 8, stream);
    vq_dist<<<2048, NT, 0, stream>>>(latent, weight, wnorm, keys);
    vq_emit<<< 512, 256, 0, stream>>>(latent, weight, keys, out);
  } else {
    vq_mono<<< 512, NT, 0, stream>>>(latent, weight, wnorm, out);
  }
}

// Round 10
// 208.253 us; speedup vs baseline: 1.5333x; 1.0850x over previous
//
#include <hip/hip_runtime.h>
#include <math.h>
#include <stdint.h>

#define DDIM   256
#define HWSZ   1024
#define NROWS  32768
#define KCODES 1024
#define BN     64
#define BK     128
#define BD     32
#define NT     256
#define WSP    132
#define TAU    4.0e-4f      // flag gap threshold (3-term err ~1e-5 + grid 3e-5)
#define VEPS   2.0e-3f      // verify threshold (layout errors are O(0.1))

// ws layout (byte offsets)
#define WS_WNORM 0                       // float[1024]           (4 KB)
#define WS_KEYS  4096                    // u64[32768]            (256 KB)
#define WS_FLAGS 266240                  // int[32768]            (128 KB)
#define WS_WHI   397312                  // bf16 hi planes        (512 KB)
#define WS_WLO   921600                  // bf16 lo planes        (512 KB)
#define WS_NEED_MFMA 1445888
#define WS_NEED_F32  266240

typedef __attribute__((ext_vector_type(8)))  short short8;
typedef __attribute__((ext_vector_type(16))) float f32x16;

__device__ __forceinline__ uint32_t fbits(float f) { return __float_as_uint(f); }
__device__ __forceinline__ float    ubits(uint32_t u) { return __uint_as_float(u); }
__device__ __forceinline__ uint32_t bf16rne(float f) {
  uint32_t u = fbits(f);
  return (u + 0x7FFFu + ((u >> 16) & 1u)) >> 16;
}
__device__ __forceinline__ uint32_t flipbits(float d) {
  uint32_t b = fbits(d);
  return (b & 0x80000000u) ? ~b : (b | 0x80000000u);
}
__device__ __forceinline__ float unflip(uint32_t x) {
  return ubits((x & 0x80000000u) ? (x & 0x7FFFFFFFu) : ~x);
}
__device__ __forceinline__ unsigned long long umin64(unsigned long long a, unsigned long long b) { return a < b ? a : b; }
__device__ __forceinline__ unsigned long long umax64(unsigned long long a, unsigned long long b) { return a > b ? a : b; }

// ---------------------------------------------------------------------------
// k1: per-code squared norms + zero the loss slot (proven, verbatim)
// ---------------------------------------------------------------------------
__global__ __launch_bounds__(256)
void vq_wnorm(const float* __restrict__ weight, float* __restrict__ wnorm,
              float* __restrict__ loss_slot) {
  const int tid  = threadIdx.x;
  const int lane = tid & 63;
  const int code = blockIdx.x * 4 + (tid >> 6);
  float4 v = *(const float4*)(weight + (size_t)code * DDIM + lane * 4);
  float s = v.x * v.x + v.y * v.y + v.z * v.z + v.w * v.w;
#pragma unroll
  for (int off = 1; off < 64; off <<= 1) s += __shfl_xor(s, off);
  if (lane == 0) wnorm[code] = s;
  if (blockIdx.x == 0 && tid == 0) *loss_slot = 0.0f;
}

// ---------------------------------------------------------------------------
// k1b: codebook -> bf16 hi/lo planes (proven layout, verbatim semantics)
// plane per 16-dim chunk: [2 oct][1024 code][8 bf16] = 32 KB
// ---------------------------------------------------------------------------
__global__ __launch_bounds__(256)
void vq_prep(const float* __restrict__ weight, char* __restrict__ ws) {
  const int t    = threadIdx.x;
  const int code = blockIdx.x * 8 + (t >> 5);
  const int l32  = t & 31;
  const int d0   = l32 * 8;
  const int ch   = l32 >> 1;
  const int slot = l32 & 1;
  const float* wr = weight + (size_t)code * DDIM + d0;
  float4 f0 = *(const float4*)(wr);
  float4 f1 = *(const float4*)(wr + 4);
  float x[8] = {f0.x, f0.y, f0.z, f0.w, f1.x, f1.y, f1.z, f1.w};
  uint32_t hp[4], lp[4];
#pragma unroll
  for (int j = 0; j < 4; ++j) {
    float a = x[2*j], b = x[2*j+1];
    uint32_t ha = bf16rne(a), hb = bf16rne(b);
    float la = a - ubits(ha << 16);
    float lb = b - ubits(hb << 16);
    hp[j] = ha | (hb << 16);
    lp[j] = bf16rne(la) | (bf16rne(lb) << 16);
  }
  const size_t off = (size_t)ch * 32768 + (size_t)slot * 16384 + (size_t)code * 16;
  *(uint4*)(ws + WS_WHI + off) = make_uint4(hp[0], hp[1], hp[2], hp[3]);
  *(uint4*)(ws + WS_WLO + off) = make_uint4(lp[0], lp[1], lp[2], lp[3]);
}

// ---------------------------------------------------------------------------
// k2: 3-term split-bf16 MFMA argmin + fused gather/transpose/loss epilogue.
// Block = 32 rows x 1024 codes, 8 waves. W read direct from L2 (no W-LDS).
// A-tile double-buffered, one barrier per chunk. Verify + gap-flag kept.
// ---------------------------------------------------------------------------
__global__ __launch_bounds__(512)
void vq_mfma3(const float* __restrict__ latent, const float* __restrict__ weight,
              char* __restrict__ ws, float* __restrict__ out) {
  __shared__ __align__(16) short AH[2][2][32][8];   // [buf][oct][row][8]  2 KB
  __shared__ __align__(16) short AL[2][2][32][8];   // 2 KB
  __shared__ ulonglong2 cand[32][8];                // 4 KB
  __shared__ unsigned long long sM1[32];
  __shared__ int sGap[32];
  __shared__ int sVer[8];
  __shared__ float sRed[8];

  const int tid  = threadIdx.x;
  const int l    = tid & 63;
  const int w    = tid >> 6;
  const int ln31 = l & 31;
  const int half = l >> 5;
  const int b    = blockIdx.x >> 5;
  const int hw0  = (blockIdx.x & 31) * 32;
  const float* lat_b = latent + (size_t)b * (DDIM * HWSZ);
  const char* whi = ws + WS_WHI;
  const char* wlo = ws + WS_WLO;
  const float* wnorm = (const float*)(ws + WS_WNORM);

  f32x16 acc[4];
#pragma unroll
  for (int cg = 0; cg < 4; ++cg) acc[cg] = (f32x16)0.0f;

  const int arow = tid & 31;     // A-stage: 32 rows x 16 dims, 1 value/thread
  const int adim = tid >> 5;

  // prologue: stage chunk 0 into buf 0
  {
    float x = lat_b[(size_t)adim * HWSZ + hw0 + arow];
    uint32_t h = bf16rne(x);
    float lo = x - ubits(h << 16);
    AH[0][adim >> 3][arow][adim & 7] = (short)h;
    AL[0][adim >> 3][arow][adim & 7] = (short)bf16rne(lo);
  }
  __syncthreads();

  for (int ch = 0; ch < 16; ++ch) {
    const int cur = ch & 1;
    float xr2 = 0.f;
    if (ch < 15)   // prefetch next chunk's latent (hidden under MFMAs)
      xr2 = lat_b[(size_t)((ch + 1) * 16 + adim) * HWSZ + hw0 + arow];

    short8 ah = *(const short8*)&AH[cur][half][ln31][0];
    short8 al = *(const short8*)&AL[cur][half][ln31][0];
#pragma unroll
    for (int cg = 0; cg < 4; ++cg) {
      const int code = w * 128 + cg * 32 + ln31;
      const size_t boff = (size_t)ch * 32768 + (size_t)half * 16384 + (size_t)code * 16;
      short8 bh = *(const short8*)(whi + boff);   // L2-resident, coalesced
      short8 bl = *(const short8*)(wlo + boff);
      acc[cg] = __builtin_amdgcn_mfma_f32_32x32x16_bf16(ah, bh, acc[cg], 0, 0, 0);
      acc[cg] = __builtin_amdgcn_mfma_f32_32x32x16_bf16(al, bh, acc[cg], 0, 0, 0);
      acc[cg] = __builtin_amdgcn_mfma_f32_32x32x16_bf16(ah, bl, acc[cg], 0, 0, 0);
    }
    if (ch < 15) {
      uint32_t h = bf16rne(xr2);
      float lo = xr2 - ubits(h << 16);
      AH[cur ^ 1][adim >> 3][arow][adim & 7] = (short)h;
      AL[cur ^ 1][adim >> 3][arow][adim & 7] = (short)bf16rne(lo);
    }
    __syncthreads();
  }

  // ---- fold: per-row best/second-best over this wave's 128 codes ----
  float wnv[4];
#pragma unroll
  for (int cg = 0; cg < 4; ++cg) wnv[cg] = wnorm[w * 128 + cg * 32 + ln31];

#pragma unroll
  for (int reg = 0; reg < 16; ++reg) {
    unsigned long long kk[4];
#pragma unroll
    for (int cg = 0; cg < 4; ++cg) {
      const int code = w * 128 + cg * 32 + ln31;
      float dk = fmaf(-2.0f, acc[cg][reg], wnv[cg]);   // xn dropped: gap-flag covers
      kk[cg] = (((unsigned long long)flipbits(dk)) << 32) | (unsigned long long)(uint32_t)code;
    }
    unsigned long long a = umin64(kk[0], kk[1]), bb = umax64(kk[0], kk[1]);
    unsigned long long c = umin64(kk[2], kk[3]), e  = umax64(kk[2], kk[3]);
    unsigned long long m1 = umin64(a, c);
    unsigned long long m2 = umin64(umin64(bb, e), umax64(a, c));
#pragma unroll
    for (int s = 1; s <= 16; s <<= 1) {
      unsigned long long om1 = __shfl_xor(m1, s);
      unsigned long long om2 = __shfl_xor(m2, s);
      unsigned long long nm2 = umin64(umin64(m2, om2), umax64(m1, om1));
      m1 = umin64(m1, om1);
      m2 = nm2;
    }
    if (ln31 == 0) {
      const int row = (reg & 3) + 8 * (reg >> 2) + 4 * half;   // verified C/D map
      cand[row][w] = make_ulonglong2(m1, m2);
    }
  }
  __syncthreads();

  // ---- merge across waves; keys plain store (single writer per row) ----
  unsigned long long* keys = (unsigned long long*)(ws + WS_KEYS);
  if (tid < 256) {
    const int row = tid >> 3, ww = tid & 7;
    ulonglong2 cc = cand[row][ww];
    unsigned long long m1 = cc.x, m2 = cc.y;
#pragma unroll
    for (int s = 1; s <= 4; s <<= 1) {
      unsigned long long om1 = __shfl_xor(m1, s);
      unsigned long long om2 = __shfl_xor(m2, s);
      unsigned long long nm2 = umin64(umin64(m2, om2), umax64(m1, om1));
      m1 = umin64(m1, om1);
      m2 = nm2;
    }
    if (ww == 0) {
      keys[blockIdx.x * 32 + row] = m1;
      float d1 = unflip((uint32_t)(m1 >> 32));
      float d2 = unflip((uint32_t)(m2 >> 32));
      sGap[row] = (d2 - d1 < TAU) ? 1 : 0;
      sM1[row]  = m1;
    }
  }
  __syncthreads();

  // ---- verify all 32 rows: exact f32 check of each claimed winner ----
  {
    int bad = 0;
#pragma unroll
    for (int i = 0; i < 4; ++i) {
      const int row = w * 4 + i;
      unsigned long long m1 = sM1[row];
      const int c = (int)(m1 & 0x3FFull);
      float d1 = unflip((uint32_t)(m1 >> 32));
      float4 wv = *(const float4*)(weight + (size_t)c * DDIM + l * 4);
      float x0 = lat_b[(size_t)(4 * l + 0) * HWSZ + hw0 + row];
      float x1 = lat_b[(size_t)(4 * l + 1) * HWSZ + hw0 + row];
      float x2 = lat_b[(size_t)(4 * l + 2) * HWSZ + hw0 + row];
      float x3 = lat_b[(size_t)(4 * l + 3) * HWSZ + hw0 + row];
      float p = x0 * wv.x + x1 * wv.y + x2 * wv.z + x3 * wv.w;
#pragma unroll
      for (int s = 1; s < 64; s <<= 1) p += __shfl_xor(p, s);
      float dex = wnorm[c] - 2.0f * p;
      bad |= (fabsf(dex - d1) > VEPS) ? 1 : 0;
    }
    if (l == 0) sVer[w] = bad;
  }
  __syncthreads();
  if (tid == 0) {
    int vb = 0;
#pragma unroll
    for (int i = 0; i < 8; ++i) vb |= sVer[i];
    sVer[0] = vb;
  }
  __syncthreads();
  if (tid < 32)
    ((int*)(ws + WS_FLAGS))[blockIdx.x * 32 + tid] = sGap[tid] | sVer[0];

  // ---- fused epilogue: gather codes, transposed write, commitment loss ----
  {
    const int er = tid & 31;
    const int eg = tid >> 5;
    const int ec = (int)(sM1[er] & 0x3FFull);
    const float* wrow = weight + (size_t)ec * DDIM;
    float* out_b = out + (size_t)b * (DDIM * HWSZ);
    float ls = 0.f;
#pragma unroll
    for (int i = 0; i < 16; ++i) {
      const int d = i * 16 + eg;
      const size_t off = (size_t)d * HWSZ + hw0 + er;
      float x  = lat_b[off];
      float qv = wrow[d];
      out_b[off] = qv;
      float e = qv - x;
      ls += e * e;
    }
#pragma unroll
    for (int s = 1; s < 64; s <<= 1) ls += __shfl_xor(ls, s);
    if (l == 0) sRed[w] = ls;
  }
  __syncthreads();
  if (tid == 0) {
    float t = 0.f;
#pragma unroll
    for (int i = 0; i < 8; ++i) t += sRed[i];
    atomicAdd(out + (size_t)NROWS * DDIM, t * (1.0f / 8388608.0f));
  }
}

// ---------------------------------------------------------------------------
// k2b: exact coarse-grid re-argmin for flagged rows (round-6 math verbatim);
// rewrites the output row and patches the loss delta.
// ---------------------------------------------------------------------------
__global__ __launch_bounds__(256)
void vq_fixc(const float* __restrict__ latent, const float* __restrict__ weight,
             char* __restrict__ ws, float* __restrict__ out) {
  __shared__ float xs[256];
  __shared__ float bd[4];
  __shared__ int   bix[4];
  __shared__ int   sNew;
  __shared__ float sDl[4];
  const int t = threadIdx.x;
  const int* flags = (const int*)(ws + WS_FLAGS);
  const float* wnorm = (const float*)(ws + WS_WNORM);
  const unsigned long long* keys = (const unsigned long long*)(ws + WS_KEYS);

  for (int rloc = 0; rloc < 64; ++rloc) {
    const int grow = blockIdx.x * 64 + rloc;
    if (!flags[grow]) continue;                      // uniform per block
    const int b = grow >> 10, hw = grow & 1023;
    __syncthreads();
    xs[t] = latent[(size_t)b * (DDIM * HWSZ) + (size_t)t * HWSZ + hw];
    __syncthreads();
    float xnv = 0.f;
    const float4* x4 = (const float4*)xs;
#pragma unroll 16
    for (int k = 0; k < 64; ++k) {
      float4 xq = x4[k];
      xnv += xq.x * xq.x; xnv += xq.y * xq.y;
      xnv += xq.z * xq.z; xnv += xq.w * xq.w;
    }
    float best = INFINITY; int bi = 0;
    for (int j = 0; j < 4; ++j) {
      const int c = 256 * j + t;
      const float4* w4 = (const float4*)(weight + (size_t)c * DDIM);
      float dot = 0.f;
#pragma unroll 16
      for (int k = 0; k < 64; ++k) {
        float4 wv = w4[k];
        dot = fmaf(xs[4*k  ], wv.x, dot);
        dot = fmaf(xs[4*k+1], wv.y, dot);
        dot = fmaf(xs[4*k+2], wv.z, dot);
        dot = fmaf(xs[4*k+3], wv.w, dot);
      }
      float dist = (xnv + wnorm[c]) - 2.0f * dot;    // coarse grid, verbatim
      if (dist < best || (dist == best && c < bi)) { best = dist; bi = c; }
    }
#pragma unroll
    for (int s = 1; s <= 32; s <<= 1) {
      float od = __shfl_xor(best, s);
      int   oi = __shfl_xor(bi, s);
      if (od < best || (od == best && oi < bi)) { best = od; bi = oi; }
    }
    if ((t & 63) == 0) { bd[t >> 6] = best; bix[t >> 6] = bi; }
    __syncthreads();
    if (t == 0) {
      float fb = bd[0]; int fbi = bix[0];
#pragma unroll
      for (int ww = 1; ww < 4; ++ww)
        if (bd[ww] < fb || (bd[ww] == fb && bix[ww] < fbi)) { fb = bd[ww]; fbi = bix[ww]; }
      sNew = fbi;
    }
    __syncthreads();
    const int newc = sNew;
    const int oldc = (int)(keys[grow] & 0x3FFull);
    const float x  = xs[t];
    const float qn = weight[(size_t)newc * DDIM + t];
    const float qo = weight[(size_t)oldc * DDIM + t];
    out[(size_t)b * (DDIM * HWSZ) + (size_t)t * HWSZ + hw] = qn;
    float dl = (qn - x) * (qn - x) - (qo - x) * (qo - x);
#pragma unroll
    for (int s = 1; s < 64; s <<= 1) dl += __shfl_xor(dl, s);
    if ((t & 63) == 0) sDl[t >> 6] = dl;
    __syncthreads();
    if (t == 0)
      atomicAdd(out + (size_t)NROWS * DDIM,
                (sDl[0] + sDl[1] + sDl[2] + sDl[3]) * (1.0f / 8388608.0f));
    __syncthreads();
  }
}

// ---------------------------------------------------------------------------
// Fallback tier 1: round-6 proven f32 kernel (verbatim)
// ---------------------------------------------------------------------------
__global__ __launch_bounds__(NT, 4)
void vq_dist(const float* __restrict__ latent, const float* __restrict__ weight,
             const float* __restrict__ wnorm,
             unsigned long long* __restrict__ keys) {
  __shared__ __align__(16) float As[BD][BN];
  __shared__ __align__(16) float Ws[BD][WSP];

  const int tid = threadIdx.x;
  const int tx  = tid & 15;
  const int ty  = tid >> 4;
  const int rb  = blockIdx.x >> 2;
  const int q   = blockIdx.x & 3;
  const int b   = rb >> 4;
  const int hw0 = (rb & 15) * BN;
  const float* lat_b = latent + (size_t)b * DDIM * HWSZ;

  float xn[4] = {0.f, 0.f, 0.f, 0.f};
  for (int dc = 0; dc < DDIM / BD; ++dc) {
    __syncthreads();
#pragma unroll
    for (int i = 0; i < 2; ++i) {
      int idx = tid + i * NT;
      int dd = idx >> 4, f4 = idx & 15;
      *(float4*)&As[dd][f4 * 4] =
          *(const float4*)(lat_b + (size_t)(dc * BD + dd) * HWSZ + hw0 + f4 * 4);
    }
    __syncthreads();
#pragma unroll 8
    for (int dd = 0; dd < BD; ++dd) {
      float4 a = *(const float4*)&As[dd][ty * 4];
      xn[0] += a.x * a.x; xn[1] += a.y * a.y;
      xn[2] += a.z * a.z; xn[3] += a.w * a.w;
    }
  }

  float best[4] = {INFINITY, INFINITY, INFINITY, INFINITY};
  int   bidx[4] = {0, 0, 0, 0};

  for (int kt = 0; kt < 2; ++kt) {
    const int k0 = q * 256 + kt * BK;
    float acc[4][8];
#pragma unroll
    for (int r = 0; r < 4; ++r)
#pragma unroll
      for (int c = 0; c < 8; ++c) acc[r][c] = 0.f;

    for (int dc = 0; dc < DDIM / BD; ++dc) {
      const int d0 = dc * BD;
      __syncthreads();
#pragma unroll
      for (int i = 0; i < 2; ++i) {
        int idx = tid + i * NT;
        int dd = idx >> 4, f4 = idx & 15;
        *(float4*)&As[dd][f4 * 4] =
            *(const float4*)(lat_b + (size_t)(d0 + dd) * HWSZ + hw0 + f4 * 4);
      }
#pragma unroll
      for (int i = 0; i < 4; ++i) {
        int idx = tid + i * NT;
        int kl = idx >> 3, df = idx & 7;
        float4 v = *(const float4*)(weight + (size_t)(k0 + kl) * DDIM + d0 + df * 4);
        Ws[df * 4 + 0][kl] = v.x;
        Ws[df * 4 + 1][kl] = v.y;
        Ws[df * 4 + 2][kl] = v.z;
        Ws[df * 4 + 3][kl] = v.w;
      }
      __syncthreads();

#pragma unroll 8
      for (int dd = 0; dd < BD; ++dd) {
        float4 a  = *(const float4*)&As[dd][ty * 4];
        float4 w0 = *(const float4*)&Ws[dd][tx * 4];
        float4 w1 = *(const float4*)&Ws[dd][64 + tx * 4];
        float av[4] = {a.x, a.y, a.z, a.w};
        float wv[8] = {w0.x, w0.y, w0.z, w0.w, w1.x, w1.y, w1.z, w1.w};
#pragma unroll
        for (int r = 0; r < 4; ++r)
#pragma unroll
          for (int c = 0; c < 8; ++c)
            acc[r][c] += av[r] * wv[c];
      }
    }

#pragma unroll
    for (int c = 0; c < 8; ++c) {
      const int kg = k0 + ((c < 4) ? (tx * 4 + c) : (64 + tx * 4 + (c - 4)));
      const float wn = wnorm[kg];
#pragma unroll
      for (int r = 0; r < 4; ++r) {
        float dist = (xn[r] + wn) - 2.0f * acc[r][c];
        if (dist < best[r] || (dist == best[r] && kg < bidx[r])) {
          best[r] = dist; bidx[r] = kg;
        }
      }
    }
  }

#pragma unroll
  for (int j = 0; j < 4; ++j) {
    float bd = best[j];
    int   bi = bidx[j];
#pragma unroll
    for (int off = 1; off < 16; off <<= 1) {
      float od = __shfl_xor(bd, off);
      int   oi = __shfl_xor(bi, off);
      if (od < bd || (od == bd && oi < bi)) { bd = od; bi = oi; }
    }
    if (tx == 0) {
      unsigned long long key =
          (((unsigned long long)flipbits(bd)) << 32) | (unsigned long long)(uint32_t)bi;
      atomicMin(&keys[rb * 64 + ty * 4 + j], key);
    }
  }
}

// ---------------------------------------------------------------------------
// Fallback tier 1 epilogue (proven vq_emit)
// ---------------------------------------------------------------------------
__global__ __launch_bounds__(256)
void vq_emit(const float* __restrict__ latent, const float* __restrict__ weight,
             const unsigned long long* __restrict__ keys, float* __restrict__ out) {
  __shared__ int   sIdx[64];
  __shared__ float sRed[4];
  const int t   = threadIdx.x;
  const int blk = blockIdx.x;
  const int b   = blk >> 4;
  const int hw0 = (blk & 15) * 64;
  if (t < 64) sIdx[t] = (int)(keys[blk * 64 + t] & 0x3FFull);
  __syncthreads();

  const int hw4  = (t & 15) * 4;
  const int dgrp = t >> 4;
  const float* lat_b = latent + (size_t)b * DDIM * HWSZ;
  float* out_b = out + (size_t)b * DDIM * HWSZ;
  const float* w0 = weight + (size_t)sIdx[hw4 + 0] * DDIM;
  const float* w1 = weight + (size_t)sIdx[hw4 + 1] * DDIM;
  const float* w2 = weight + (size_t)sIdx[hw4 + 2] * DDIM;
  const float* w3 = weight + (size_t)sIdx[hw4 + 3] * DDIM;
  float lsum = 0.f;
#pragma unroll
  for (int it = 0; it < 16; ++it) {
    const int d = it * 16 + dgrp;
    float4 xv = *(const float4*)(lat_b + (size_t)d * HWSZ + hw0 + hw4);
    float q0 = w0[d], q1 = w1[d], q2 = w2[d], q3 = w3[d];
    *(float4*)(out_b + (size_t)d * HWSZ + hw0 + hw4) = make_float4(q0, q1, q2, q3);
    float e0 = q0 - xv.x, e1 = q1 - xv.y, e2 = q2 - xv.z, e3 = q3 - xv.w;
    lsum += e0 * e0 + e1 * e1 + e2 * e2 + e3 * e3;
  }
#pragma unroll
  for (int s = 1; s < 64; s <<= 1) lsum += __shfl_xor(lsum, s);
  if ((t & 63) == 0) sRed[t >> 6] = lsum;
  __syncthreads();
  if (t == 0) {
    float tot = sRed[0] + sRed[1] + sRed[2] + sRed[3];
    atomicAdd(out + (size_t)NROWS * DDIM, tot * (1.0f / 8388608.0f));
  }
}

// ---------------------------------------------------------------------------
// Fallback tier 2: mono (round-1 structure, proven semantics)
// ---------------------------------------------------------------------------
__global__ __launch_bounds__(NT, 2)
void vq_mono(const float* __restrict__ latent, const float* __restrict__ weight,
             const float* __restrict__ wnorm, float* __restrict__ out) {
  __shared__ __align__(16) float As[BD][BN];
  __shared__ __align__(16) float Ws[BD][WSP];
  __shared__ int   sIdx[BN];
  __shared__ float sRed[4];

  const int tid = threadIdx.x;
  const int blk = blockIdx.x;
  const int tx  = tid & 15;
  const int ty  = tid >> 4;
  const int b   = blk >> 4;
  const int hw0 = (blk & 15) * BN;
  const float* lat_b = latent + (size_t)b * DDIM * HWSZ;

  float xn[4] = {0.f, 0.f, 0.f, 0.f};
  for (int dc = 0; dc < DDIM / BD; ++dc) {
    __syncthreads();
#pragma unroll
    for (int i = 0; i < 2; ++i) {
      int idx = tid + i * NT;
      int dd = idx >> 4, f4 = idx & 15;
      *(float4*)&As[dd][f4 * 4] =
          *(const float4*)(lat_b + (size_t)(dc * BD + dd) * HWSZ + hw0 + f4 * 4);
    }
    __syncthreads();
#pragma unroll 8
    for (int dd = 0; dd < BD; ++dd) {
      float4 a = *(const float4*)&As[dd][ty * 4];
      xn[0] += a.x * a.x; xn[1] += a.y * a.y;
      xn[2] += a.z * a.z; xn[3] += a.w * a.w;
    }
  }

  float best[4] = {INFINITY, INFINITY, INFINITY, INFINITY};
  int   bidx[4] = {0, 0, 0, 0};

  for (int kt = 0; kt < KCODES / BK; ++kt) {
    const int k0 = kt * BK;
    float acc[4][8];
#pragma unroll
    for (int r = 0; r < 4; ++r)
#pragma unroll
      for (int c = 0; c < 8; ++c) acc[r][c] = 0.f;

    for (int dc = 0; dc < DDIM / BD; ++dc) {
      const int d0 = dc * BD;
      __syncthreads();
#pragma unroll
      for (int i = 0; i < 2; ++i) {
        int idx = tid + i * NT;
        int dd = idx >> 4, f4 = idx & 15;
        *(float4*)&As[dd][f4 * 4] =
            *(const float4*)(lat_b + (size_t)(d0 + dd) * HWSZ + hw0 + f4 * 4);
      }
#pragma unroll
      for (int i = 0; i < 4; ++i) {
        int idx = tid + i * NT;
        int kl = idx >> 3, df = idx & 7;
        float4 v = *(const float4*)(weight + (size_t)(k0 + kl) * DDIM + d0 + df * 4);
        Ws[df * 4 + 0][kl] = v.x;
        Ws[df * 4 + 1][kl] = v.y;
        Ws[df * 4 + 2][kl] = v.z;
        Ws[df * 4 + 3][kl] = v.w;
      }
      __syncthreads();

#pragma unroll 8
      for (int dd = 0; dd < BD; ++dd) {
        float4 a  = *(const float4*)&As[dd][ty * 4];
        float4 w0 = *(const float4*)&Ws[dd][tx * 4];
        float4 w1 = *(const float4*)&Ws[dd][64 + tx * 4];
        float av[4] = {a.x, a.y, a.z, a.w};
        float wv[8] = {w0.x, w0.y, w0.z, w0.w, w1.x, w1.y, w1.z, w1.w};
#pragma unroll
        for (int r = 0; r < 4; ++r)
#pragma unroll
          for (int c = 0; c < 8; ++c)
            acc[r][c] += av[r] * wv[c];
      }
    }

#pragma unroll
    for (int c = 0; c < 8; ++c) {
      const int kg = k0 + ((c < 4) ? (tx * 4 + c) : (64 + tx * 4 + (c - 4)));
      const float wn = wnorm[kg];
#pragma unroll
      for (int r = 0; r < 4; ++r) {
        float dist = (xn[r] + wn) - 2.0f * acc[r][c];
        if (dist < best[r] || (dist == best[r] && kg < bidx[r])) {
          best[r] = dist; bidx[r] = kg;
        }
      }
    }
  }

#pragma unroll
  for (int j = 0; j < 4; ++j) {
    float bd = best[j];
    int   bi = bidx[j];
#pragma unroll
    for (int off = 1; off < 16; off <<= 1) {
      float od = __shfl_xor(bd, off);
      int   oi = __shfl_xor(bi, off);
      if (od < bd || (od == bd && oi < bi)) { bd = od; bi = oi; }
    }
    if (tx == 0) sIdx[ty * 4 + j] = bi;
  }
  __syncthreads();

  const int hwl = tid & 63;
  const int wv  = tid >> 6;
  const int ksel = sIdx[hwl];
  const float* wrow = weight + (size_t)ksel * DDIM;
  float lsum = 0.f;
#pragma unroll 4
  for (int it = 0; it < 64; ++it) {
    int d = it * 4 + wv;
    size_t off = (size_t)d * HWSZ + hw0 + hwl;
    float x = lat_b[off];
    float qv = wrow[d];
    out[(size_t)b * DDIM * HWSZ + off] = qv;
    float df = qv - x;
    lsum += df * df;
  }
#pragma unroll
  for (int off = 1; off < 64; off <<= 1) lsum += __shfl_xor(lsum, off);
  if ((tid & 63) == 0) sRed[tid >> 6] = lsum;
  __syncthreads();
  if (tid == 0) {
    float t = sRed[0] + sRed[1] + sRed[2] + sRed[3];
    atomicAdd(out + (size_t)NROWS * DDIM, t * (1.0f / ((float)NROWS * (float)DDIM)));
  }
}

// ---------------------------------------------------------------------------
extern "C" void kernel_launch(void* const* d_in, const int* in_sizes, int n_in,
                              void* d_out, int out_size, void* d_ws, size_t ws_size,
                              hipStream_t stream) {
  const float* latent = (const float*)d_in[0];   // (32,256,32,32) f32
  const float* weight = (const float*)d_in[1];   // (1024,256)     f32
  float* out   = (float*)d_out;                  // 8388608 + 1 (loss)
  char*  ws    = (char*)d_ws;
  float* wnorm = (float*)(ws + WS_WNORM);

  vq_wnorm<<<KCODES / 4, 256, 0, stream>>>(weight, wnorm, out + (size_t)NROWS * DDIM);

  if (ws_size >= (size_t)WS_NEED_MFMA) {
    vq_prep <<<KCODES / 8, 256, 0, stream>>>(weight, ws);
    vq_mfma3<<<1024, 512, 0, stream>>>(latent, weight, ws, out);
    vq_fixc <<< 512, 256, 0, stream>>>(latent, weight, ws, out);
  } else if (ws_size >= (size_t)WS_NEED_F32) {
    unsigned long long* keys = (unsigned long long*)(ws + WS_KEYS);
    hipMemsetAsync(ws + WS_KEYS, 0xFF, (size_t)NROWS * 8, stream);
    vq_dist<<<2048, NT, 0, stream>>>(latent, weight, wnorm, keys);
    vq_emit<<< 512, 256, 0, stream>>>(latent, weight, keys, out);
  } else {
    vq_mono<<< 512, NT, 0, stream>>>(latent, weight, wnorm, out);
  }
}

// Round 11
// 199.897 us; speedup vs baseline: 1.5974x; 1.0418x over previous
//
#include <hip/hip_runtime.h>
#include <math.h>
#include <stdint.h>

#define DDIM   256
#define HWSZ   1024
#define NROWS  32768
#define KCODES 1024
#define BN     64
#define BK     128
#define BD     32
#define NT     256
#define WSP    132
#define TAU    4.0e-4f      // flag gap threshold (3-term err ~1e-5 + grid 3e-5)
#define VEPS   2.0e-3f      // verify threshold (layout errors are O(0.1))

// ws layout (byte offsets)
#define WS_WNORM 0                       // float[1024]           (4 KB)
#define WS_KEYS  4096                    // u64[32768]            (256 KB)
#define WS_FLAGS 266240                  // int[32768]            (128 KB)
#define WS_WHI   397312                  // bf16 hi planes        (512 KB)
#define WS_WLO   921600                  // bf16 lo planes        (512 KB)
#define WS_NEED_MFMA 1445888
#define WS_NEED_F32  266240

typedef __attribute__((ext_vector_type(8)))  short short8;
typedef __attribute__((ext_vector_type(16))) float f32x16;

__device__ __forceinline__ uint32_t fbits(float f) { return __float_as_uint(f); }
__device__ __forceinline__ float    ubits(uint32_t u) { return __uint_as_float(u); }
__device__ __forceinline__ uint32_t bf16rne(float f) {
  uint32_t u = fbits(f);
  return (u + 0x7FFFu + ((u >> 16) & 1u)) >> 16;
}
__device__ __forceinline__ uint32_t flipbits(float d) {
  uint32_t b = fbits(d);
  return (b & 0x80000000u) ? ~b : (b | 0x80000000u);
}
__device__ __forceinline__ float unflip(uint32_t x) {
  return ubits((x & 0x80000000u) ? (x & 0x7FFFFFFFu) : ~x);
}
__device__ __forceinline__ unsigned long long umin64(unsigned long long a, unsigned long long b) { return a < b ? a : b; }
__device__ __forceinline__ unsigned long long umax64(unsigned long long a, unsigned long long b) { return a > b ? a : b; }

// ---------------------------------------------------------------------------
// k1: per-code squared norms + zero the loss slot (proven, verbatim)
// ---------------------------------------------------------------------------
__global__ __launch_bounds__(256)
void vq_wnorm(const float* __restrict__ weight, float* __restrict__ wnorm,
              float* __restrict__ loss_slot) {
  const int tid  = threadIdx.x;
  const int lane = tid & 63;
  const int code = blockIdx.x * 4 + (tid >> 6);
  float4 v = *(const float4*)(weight + (size_t)code * DDIM + lane * 4);
  float s = v.x * v.x + v.y * v.y + v.z * v.z + v.w * v.w;
#pragma unroll
  for (int off = 1; off < 64; off <<= 1) s += __shfl_xor(s, off);
  if (lane == 0) wnorm[code] = s;
  if (blockIdx.x == 0 && tid == 0) *loss_slot = 0.0f;
}

// ---------------------------------------------------------------------------
// k1b: codebook -> bf16 hi/lo planes (proven layout, verbatim)
// plane per 16-dim chunk: [2 oct][1024 code][8 bf16] = 32 KB
// ---------------------------------------------------------------------------
__global__ __launch_bounds__(256)
void vq_prep(const float* __restrict__ weight, char* __restrict__ ws) {
  const int t    = threadIdx.x;
  const int code = blockIdx.x * 8 + (t >> 5);
  const int l32  = t & 31;
  const int d0   = l32 * 8;
  const int ch   = l32 >> 1;
  const int slot = l32 & 1;
  const float* wr = weight + (size_t)code * DDIM + d0;
  float4 f0 = *(const float4*)(wr);
  float4 f1 = *(const float4*)(wr + 4);
  float x[8] = {f0.x, f0.y, f0.z, f0.w, f1.x, f1.y, f1.z, f1.w};
  uint32_t hp[4], lp[4];
#pragma unroll
  for (int j = 0; j < 4; ++j) {
    float a = x[2*j], b = x[2*j+1];
    uint32_t ha = bf16rne(a), hb = bf16rne(b);
    float la = a - ubits(ha << 16);
    float lb = b - ubits(hb << 16);
    hp[j] = ha | (hb << 16);
    lp[j] = bf16rne(la) | (bf16rne(lb) << 16);
  }
  const size_t off = (size_t)ch * 32768 + (size_t)slot * 16384 + (size_t)code * 16;
  *(uint4*)(ws + WS_WHI + off) = make_uint4(hp[0], hp[1], hp[2], hp[3]);
  *(uint4*)(ws + WS_WLO + off) = make_uint4(lp[0], lp[1], lp[2], lp[3]);
}

// ---------------------------------------------------------------------------
// k2: 3-term split-bf16 MFMA argmin, BARRIER-FREE main loop:
// A (32 rows x 256 dims, hi/lo bf16 = 32 KB) staged in LDS ONCE, then
// 16 chunks x 4 cg x 3 MFMAs with B streamed from L2 — no syncs inside.
// Fused gather/transpose/loss epilogue. Verify + gap-flag kept verbatim.
// ---------------------------------------------------------------------------
__global__ __launch_bounds__(512)
void vq_mfma3(const float* __restrict__ latent, const float* __restrict__ weight,
              char* __restrict__ ws, float* __restrict__ out) {
  __shared__ __align__(16) short AH[16][2][32][8];  // 16 KB [ch][oct][row][8]
  __shared__ __align__(16) short AL[16][2][32][8];  // 16 KB
  __shared__ ulonglong2 cand[32][8];                // 4 KB
  __shared__ unsigned long long sM1[32];
  __shared__ int sGap[32];
  __shared__ int sVer[8];
  __shared__ float sRed[8];

  const int tid  = threadIdx.x;
  const int l    = tid & 63;
  const int w    = tid >> 6;
  const int ln31 = l & 31;
  const int half = l >> 5;
  const int b    = blockIdx.x >> 5;
  const int hw0  = (blockIdx.x & 31) * 32;
  const float* lat_b = latent + (size_t)b * (DDIM * HWSZ);
  const char* whi = ws + WS_WHI;
  const char* wlo = ws + WS_WLO;
  const float* wnorm = (const float*)(ws + WS_WNORM);

  f32x16 acc[4];
#pragma unroll
  for (int cg = 0; cg < 4; ++cg) acc[cg] = (f32x16)0.0f;

  // ---- stage ALL of A once: thread (arow, adim) covers 16 chunks ----
  {
    const int arow = tid & 31;
    const int adim = tid >> 5;          // 0..15
#pragma unroll 4
    for (int ch = 0; ch < 16; ++ch) {
      float x = lat_b[(size_t)(ch * 16 + adim) * HWSZ + hw0 + arow];
      uint32_t h = bf16rne(x);
      float lo = x - ubits(h << 16);
      AH[ch][adim >> 3][arow][adim & 7] = (short)h;
      AL[ch][adim >> 3][arow][adim & 7] = (short)bf16rne(lo);
    }
  }
  __syncthreads();   // the ONLY barrier before the fold

  // ---- barrier-free MFMA loop ----
#pragma unroll 1
  for (int ch = 0; ch < 16; ++ch) {
    short8 ah = *(const short8*)&AH[ch][half][ln31][0];
    short8 al = *(const short8*)&AL[ch][half][ln31][0];
#pragma unroll
    for (int cg = 0; cg < 4; ++cg) {
      const int code = w * 128 + cg * 32 + ln31;
      const size_t boff = (size_t)ch * 32768 + (size_t)half * 16384 + (size_t)code * 16;
      short8 bh = *(const short8*)(whi + boff);   // L2-resident, coalesced
      short8 bl = *(const short8*)(wlo + boff);
      acc[cg] = __builtin_amdgcn_mfma_f32_32x32x16_bf16(ah, bh, acc[cg], 0, 0, 0);
      acc[cg] = __builtin_amdgcn_mfma_f32_32x32x16_bf16(al, bh, acc[cg], 0, 0, 0);
      acc[cg] = __builtin_amdgcn_mfma_f32_32x32x16_bf16(ah, bl, acc[cg], 0, 0, 0);
    }
  }

  // ---- fold: per-row best/second-best over this wave's 128 codes ----
  float wnv[4];
#pragma unroll
  for (int cg = 0; cg < 4; ++cg) wnv[cg] = wnorm[w * 128 + cg * 32 + ln31];

#pragma unroll
  for (int reg = 0; reg < 16; ++reg) {
    unsigned long long kk[4];
#pragma unroll
    for (int cg = 0; cg < 4; ++cg) {
      const int code = w * 128 + cg * 32 + ln31;
      float dk = fmaf(-2.0f, acc[cg][reg], wnv[cg]);   // xn dropped: gap-flag covers
      kk[cg] = (((unsigned long long)flipbits(dk)) << 32) | (unsigned long long)(uint32_t)code;
    }
    unsigned long long a = umin64(kk[0], kk[1]), bb = umax64(kk[0], kk[1]);
    unsigned long long c = umin64(kk[2], kk[3]), e  = umax64(kk[2], kk[3]);
    unsigned long long m1 = umin64(a, c);
    unsigned long long m2 = umin64(umin64(bb, e), umax64(a, c));
#pragma unroll
    for (int s = 1; s <= 16; s <<= 1) {
      unsigned long long om1 = __shfl_xor(m1, s);
      unsigned long long om2 = __shfl_xor(m2, s);
      unsigned long long nm2 = umin64(umin64(m2, om2), umax64(m1, om1));
      m1 = umin64(m1, om1);
      m2 = nm2;
    }
    if (ln31 == 0) {
      const int row = (reg & 3) + 8 * (reg >> 2) + 4 * half;   // verified C/D map
      cand[row][w] = make_ulonglong2(m1, m2);
    }
  }
  __syncthreads();

  // ---- merge across waves; keys plain store (single writer per row) ----
  unsigned long long* keys = (unsigned long long*)(ws + WS_KEYS);
  if (tid < 256) {
    const int row = tid >> 3, ww = tid & 7;
    ulonglong2 cc = cand[row][ww];
    unsigned long long m1 = cc.x, m2 = cc.y;
#pragma unroll
    for (int s = 1; s <= 4; s <<= 1) {
      unsigned long long om1 = __shfl_xor(m1, s);
      unsigned long long om2 = __shfl_xor(m2, s);
      unsigned long long nm2 = umin64(umin64(m2, om2), umax64(m1, om1));
      m1 = umin64(m1, om1);
      m2 = nm2;
    }
    if (ww == 0) {
      keys[blockIdx.x * 32 + row] = m1;
      float d1 = unflip((uint32_t)(m1 >> 32));
      float d2 = unflip((uint32_t)(m2 >> 32));
      sGap[row] = (d2 - d1 < TAU) ? 1 : 0;
      sM1[row]  = m1;
    }
  }
  __syncthreads();

  // ---- verify all 32 rows: exact f32 check of each claimed winner ----
  {
    int bad = 0;
#pragma unroll
    for (int i = 0; i < 4; ++i) {
      const int row = w * 4 + i;
      unsigned long long m1 = sM1[row];
      const int c = (int)(m1 & 0x3FFull);
      float d1 = unflip((uint32_t)(m1 >> 32));
      float4 wv = *(const float4*)(weight + (size_t)c * DDIM + l * 4);
      float x0 = lat_b[(size_t)(4 * l + 0) * HWSZ + hw0 + row];
      float x1 = lat_b[(size_t)(4 * l + 1) * HWSZ + hw0 + row];
      float x2 = lat_b[(size_t)(4 * l + 2) * HWSZ + hw0 + row];
      float x3 = lat_b[(size_t)(4 * l + 3) * HWSZ + hw0 + row];
      float p = x0 * wv.x + x1 * wv.y + x2 * wv.z + x3 * wv.w;
#pragma unroll
      for (int s = 1; s < 64; s <<= 1) p += __shfl_xor(p, s);
      float dex = wnorm[c] - 2.0f * p;
      bad |= (fabsf(dex - d1) > VEPS) ? 1 : 0;
    }
    if (l == 0) sVer[w] = bad;
  }
  __syncthreads();
  if (tid == 0) {
    int vb = 0;
#pragma unroll
    for (int i = 0; i < 8; ++i) vb |= sVer[i];
    sVer[0] = vb;
  }
  __syncthreads();
  if (tid < 32)
    ((int*)(ws + WS_FLAGS))[blockIdx.x * 32 + tid] = sGap[tid] | sVer[0];

  // ---- fused epilogue: gather codes, transposed write, commitment loss ----
  {
    const int er = tid & 31;
    const int eg = tid >> 5;
    const int ec = (int)(sM1[er] & 0x3FFull);
    const float* wrow = weight + (size_t)ec * DDIM;
    float* out_b = out + (size_t)b * (DDIM * HWSZ);
    float ls = 0.f;
#pragma unroll
    for (int i = 0; i < 16; ++i) {
      const int d = i * 16 + eg;
      const size_t off = (size_t)d * HWSZ + hw0 + er;
      float x  = lat_b[off];
      float qv = wrow[d];
      out_b[off] = qv;
      float e = qv - x;
      ls += e * e;
    }
#pragma unroll
    for (int s = 1; s < 64; s <<= 1) ls += __shfl_xor(ls, s);
    if (l == 0) sRed[w] = ls;
  }
  __syncthreads();
  if (tid == 0) {
    float t = 0.f;
#pragma unroll
    for (int i = 0; i < 8; ++i) t += sRed[i];
    atomicAdd(out + (size_t)NROWS * DDIM, t * (1.0f / 8388608.0f));
  }
}

// ---------------------------------------------------------------------------
// k2b: exact coarse-grid re-argmin for flagged rows (round-6 math verbatim);
// rewrites the output row and patches the loss delta.
// ---------------------------------------------------------------------------
__global__ __launch_bounds__(256)
void vq_fixc(const float* __restrict__ latent, const float* __restrict__ weight,
             char* __restrict__ ws, float* __restrict__ out) {
  __shared__ float xs[256];
  __shared__ float bd[4];
  __shared__ int   bix[4];
  __shared__ int   sNew;
  __shared__ float sDl[4];
  const int t = threadIdx.x;
  const int* flags = (const int*)(ws + WS_FLAGS);
  const float* wnorm = (const float*)(ws + WS_WNORM);
  const unsigned long long* keys = (const unsigned long long*)(ws + WS_KEYS);

  for (int rloc = 0; rloc < 64; ++rloc) {
    const int grow = blockIdx.x * 64 + rloc;
    if (!flags[grow]) continue;                      // uniform per block
    const int b = grow >> 10, hw = grow & 1023;
    __syncthreads();
    xs[t] = latent[(size_t)b * (DDIM * HWSZ) + (size_t)t * HWSZ + hw];
    __syncthreads();
    float xnv = 0.f;
    const float4* x4 = (const float4*)xs;
#pragma unroll 16
    for (int k = 0; k < 64; ++k) {
      float4 xq = x4[k];
      xnv += xq.x * xq.x; xnv += xq.y * xq.y;
      xnv += xq.z * xq.z; xnv += xq.w * xq.w;
    }
    float best = INFINITY; int bi = 0;
    for (int j = 0; j < 4; ++j) {
      const int c = 256 * j + t;
      const float4* w4 = (const float4*)(weight + (size_t)c * DDIM);
      float dot = 0.f;
#pragma unroll 16
      for (int k = 0; k < 64; ++k) {
        float4 wv = w4[k];
        dot = fmaf(xs[4*k  ], wv.x, dot);
        dot = fmaf(xs[4*k+1], wv.y, dot);
        dot = fmaf(xs[4*k+2], wv.z, dot);
        dot = fmaf(xs[4*k+3], wv.w, dot);
      }
      float dist = (xnv + wnorm[c]) - 2.0f * dot;    // coarse grid, verbatim
      if (dist < best || (dist == best && c < bi)) { best = dist; bi = c; }
    }
#pragma unroll
    for (int s = 1; s <= 32; s <<= 1) {
      float od = __shfl_xor(best, s);
      int   oi = __shfl_xor(bi, s);
      if (od < best || (od == best && oi < bi)) { best = od; bi = oi; }
    }
    if ((t & 63) == 0) { bd[t >> 6] = best; bix[t >> 6] = bi; }
    __syncthreads();
    if (t == 0) {
      float fb = bd[0]; int fbi = bix[0];
#pragma unroll
      for (int ww = 1; ww < 4; ++ww)
        if (bd[ww] < fb || (bd[ww] == fb && bix[ww] < fbi)) { fb = bd[ww]; fbi = bix[ww]; }
      sNew = fbi;
    }
    __syncthreads();
    const int newc = sNew;
    const int oldc = (int)(keys[grow] & 0x3FFull);
    const float x  = xs[t];
    const float qn = weight[(size_t)newc * DDIM + t];
    const float qo = weight[(size_t)oldc * DDIM + t];
    out[(size_t)b * (DDIM * HWSZ) + (size_t)t * HWSZ + hw] = qn;
    float dl = (qn - x) * (qn - x) - (qo - x) * (qo - x);
#pragma unroll
    for (int s = 1; s < 64; s <<= 1) dl += __shfl_xor(dl, s);
    if ((t & 63) == 0) sDl[t >> 6] = dl;
    __syncthreads();
    if (t == 0)
      atomicAdd(out + (size_t)NROWS * DDIM,
                (sDl[0] + sDl[1] + sDl[2] + sDl[3]) * (1.0f / 8388608.0f));
    __syncthreads();
  }
}

// ---------------------------------------------------------------------------
// Fallback tier 1: round-6 proven f32 kernel (verbatim)
// ---------------------------------------------------------------------------
__global__ __launch_bounds__(NT, 4)
void vq_dist(const float* __restrict__ latent, const float* __restrict__ weight,
             const float* __restrict__ wnorm,
             unsigned long long* __restrict__ keys) {
  __shared__ __align__(16) float As[BD][BN];
  __shared__ __align__(16) float Ws[BD][WSP];

  const int tid = threadIdx.x;
  const int tx  = tid & 15;
  const int ty  = tid >> 4;
  const int rb  = blockIdx.x >> 2;
  const int q   = blockIdx.x & 3;
  const int b   = rb >> 4;
  const int hw0 = (rb & 15) * BN;
  const float* lat_b = latent + (size_t)b * DDIM * HWSZ;

  float xn[4] = {0.f, 0.f, 0.f, 0.f};
  for (int dc = 0; dc < DDIM / BD; ++dc) {
    __syncthreads();
#pragma unroll
    for (int i = 0; i < 2; ++i) {
      int idx = tid + i * NT;
      int dd = idx >> 4, f4 = idx & 15;
      *(float4*)&As[dd][f4 * 4] =
          *(const float4*)(lat_b + (size_t)(dc * BD + dd) * HWSZ + hw0 + f4 * 4);
    }
    __syncthreads();
#pragma unroll 8
    for (int dd = 0; dd < BD; ++dd) {
      float4 a = *(const float4*)&As[dd][ty * 4];
      xn[0] += a.x * a.x; xn[1] += a.y * a.y;
      xn[2] += a.z * a.z; xn[3] += a.w * a.w;
    }
  }

  float best[4] = {INFINITY, INFINITY, INFINITY, INFINITY};
  int   bidx[4] = {0, 0, 0, 0};

  for (int kt = 0; kt < 2; ++kt) {
    const int k0 = q * 256 + kt * BK;
    float acc[4][8];
#pragma unroll
    for (int r = 0; r < 4; ++r)
#pragma unroll
      for (int c = 0; c < 8; ++c) acc[r][c] = 0.f;

    for (int dc = 0; dc < DDIM / BD; ++dc) {
      const int d0 = dc * BD;
      __syncthreads();
#pragma unroll
      for (int i = 0; i < 2; ++i) {
        int idx = tid + i * NT;
        int dd = idx >> 4, f4 = idx & 15;
        *(float4*)&As[dd][f4 * 4] =
            *(const float4*)(lat_b + (size_t)(d0 + dd) * HWSZ + hw0 + f4 * 4);
      }
#pragma unroll
      for (int i = 0; i < 4; ++i) {
        int idx = tid + i * NT;
        int kl = idx >> 3, df = idx & 7;
        float4 v = *(const float4*)(weight + (size_t)(k0 + kl) * DDIM + d0 + df * 4);
        Ws[df * 4 + 0][kl] = v.x;
        Ws[df * 4 + 1][kl] = v.y;
        Ws[df * 4 + 2][kl] = v.z;
        Ws[df * 4 + 3][kl] = v.w;
      }
      __syncthreads();

#pragma unroll 8
      for (int dd = 0; dd < BD; ++dd) {
        float4 a  = *(const float4*)&As[dd][ty * 4];
        float4 w0 = *(const float4*)&Ws[dd][tx * 4];
        float4 w1 = *(const float4*)&Ws[dd][64 + tx * 4];
        float av[4] = {a.x, a.y, a.z, a.w};
        float wv[8] = {w0.x, w0.y, w0.z, w0.w, w1.x, w1.y, w1.z, w1.w};
#pragma unroll
        for (int r = 0; r < 4; ++r)
#pragma unroll
          for (int c = 0; c < 8; ++c)
            acc[r][c] += av[r] * wv[c];
      }
    }

#pragma unroll
    for (int c = 0; c < 8; ++c) {
      const int kg = k0 + ((c < 4) ? (tx * 4 + c) : (64 + tx * 4 + (c - 4)));
      const float wn = wnorm[kg];
#pragma unroll
      for (int r = 0; r < 4; ++r) {
        float dist = (xn[r] + wn) - 2.0f * acc[r][c];
        if (dist < best[r] || (dist == best[r] && kg < bidx[r])) {
          best[r] = dist; bidx[r] = kg;
        }
      }
    }
  }

#pragma unroll
  for (int j = 0; j < 4; ++j) {
    float bd = best[j];
    int   bi = bidx[j];
#pragma unroll
    for (int off = 1; off < 16; off <<= 1) {
      float od = __shfl_xor(bd, off);
      int   oi = __shfl_xor(bi, off);
      if (od < bd || (od == bd && oi < bi)) { bd = od; bi = oi; }
    }
    if (tx == 0) {
      unsigned long long key =
          (((unsigned long long)flipbits(bd)) << 32) | (unsigned long long)(uint32_t)bi;
      atomicMin(&keys[rb * 64 + ty * 4 + j], key);
    }
  }
}

// ---------------------------------------------------------------------------
// Fallback tier 1 epilogue (proven vq_emit)
// ---------------------------------------------------------------------------
__global__ __launch_bounds__(256)
void vq_emit(const float* __restrict__ latent, const float* __restrict__ weight,
             const unsigned long long* __restrict__ keys, float* __restrict__ out) {
  __shared__ int   sIdx[64];
  __shared__ float sRed[4];
  const int t   = threadIdx.x;
  const int blk = blockIdx.x;
  const int b   = blk >> 4;
  const int hw0 = (blk & 15) * 64;
  if (t < 64) sIdx[t] = (int)(keys[blk * 64 + t] & 0x3FFull);
  __syncthreads();

  const int hw4  = (t & 15) * 4;
  const int dgrp = t >> 4;
  const float* lat_b = latent + (size_t)b * DDIM * HWSZ;
  float* out_b = out + (size_t)b * DDIM * HWSZ;
  const float* w0 = weight + (size_t)sIdx[hw4 + 0] * DDIM;
  const float* w1 = weight + (size_t)sIdx[hw4 + 1] * DDIM;
  const float* w2 = weight + (size_t)sIdx[hw4 + 2] * DDIM;
  const float* w3 = weight + (size_t)sIdx[hw4 + 3] * DDIM;
  float lsum = 0.f;
#pragma unroll
  for (int it = 0; it < 16; ++it) {
    const int d = it * 16 + dgrp;
    float4 xv = *(const float4*)(lat_b + (size_t)d * HWSZ + hw0 + hw4);
    float q0 = w0[d], q1 = w1[d], q2 = w2[d], q3 = w3[d];
    *(float4*)(out_b + (size_t)d * HWSZ + hw0 + hw4) = make_float4(q0, q1, q2, q3);
    float e0 = q0 - xv.x, e1 = q1 - xv.y, e2 = q2 - xv.z, e3 = q3 - xv.w;
    lsum += e0 * e0 + e1 * e1 + e2 * e2 + e3 * e3;
  }
#pragma unroll
  for (int s = 1; s < 64; s <<= 1) lsum += __shfl_xor(lsum, s);
  if ((t & 63) == 0) sRed[t >> 6] = lsum;
  __syncthreads();
  if (t == 0) {
    float tot = sRed[0] + sRed[1] + sRed[2] + sRed[3];
    atomicAdd(out + (size_t)NROWS * DDIM, tot * (1.0f / 8388608.0f));
  }
}

// ---------------------------------------------------------------------------
// Fallback tier 2: mono (round-1 structure, proven semantics)
// ---------------------------------------------------------------------------
__global__ __launch_bounds__(NT, 2)
void vq_mono(const float* __restrict__ latent, const float* __restrict__ weight,
             const float* __restrict__ wnorm, float* __restrict__ out) {
  __shared__ __align__(16) float As[BD][BN];
  __shared__ __align__(16) float Ws[BD][WSP];
  __shared__ int   sIdx[BN];
  __shared__ float sRed[4];

  const int tid = threadIdx.x;
  const int blk = blockIdx.x;
  const int tx  = tid & 15;
  const int ty  = tid >> 4;
  const int b   = blk >> 4;
  const int hw0 = (blk & 15) * BN;
  const float* lat_b = latent + (size_t)b * DDIM * HWSZ;

  float xn[4] = {0.f, 0.f, 0.f, 0.f};
  for (int dc = 0; dc < DDIM / BD; ++dc) {
    __syncthreads();
#pragma unroll
    for (int i = 0; i < 2; ++i) {
      int idx = tid + i * NT;
      int dd = idx >> 4, f4 = idx & 15;
      *(float4*)&As[dd][f4 * 4] =
          *(const float4*)(lat_b + (size_t)(dc * BD + dd) * HWSZ + hw0 + f4 * 4);
    }
    __syncthreads();
#pragma unroll 8
    for (int dd = 0; dd < BD; ++dd) {
      float4 a = *(const float4*)&As[dd][ty * 4];
      xn[0] += a.x * a.x; xn[1] += a.y * a.y;
      xn[2] += a.z * a.z; xn[3] += a.w * a.w;
    }
  }

  float best[4] = {INFINITY, INFINITY, INFINITY, INFINITY};
  int   bidx[4] = {0, 0, 0, 0};

  for (int kt = 0; kt < KCODES / BK; ++kt) {
    const int k0 = kt * BK;
    float acc[4][8];
#pragma unroll
    for (int r = 0; r < 4; ++r)
#pragma unroll
      for (int c = 0; c < 8; ++c) acc[r][c] = 0.f;

    for (int dc = 0; dc < DDIM / BD; ++dc) {
      const int d0 = dc * BD;
      __syncthreads();
#pragma unroll
      for (int i = 0; i < 2; ++i) {
        int idx = tid + i * NT;
        int dd = idx >> 4, f4 = idx & 15;
        *(float4*)&As[dd][f4 * 4] =
            *(const float4*)(lat_b + (size_t)(d0 + dd) * HWSZ + hw0 + f4 * 4);
      }
#pragma unroll
      for (int i = 0; i < 4; ++i) {
        int idx = tid + i * NT;
        int kl = idx >> 3, df = idx & 7;
        float4 v = *(const float4*)(weight + (size_t)(k0 + kl) * DDIM + d0 + df * 4);
        Ws[df * 4 + 0][kl] = v.x;
        Ws[df * 4 + 1][kl] = v.y;
        Ws[df * 4 + 2][kl] = v.z;
        Ws[df * 4 + 3][kl] = v.w;
      }
      __syncthreads();

#pragma unroll 8
      for (int dd = 0; dd < BD; ++dd) {
        float4 a  = *(const float4*)&As[dd][ty * 4];
        float4 w0 = *(const float4*)&Ws[dd][tx * 4];
        float4 w1 = *(const float4*)&Ws[dd][64 + tx * 4];
        float av[4] = {a.x, a.y, a.z, a.w};
        float wv[8] = {w0.x, w0.y, w0.z, w0.w, w1.x, w1.y, w1.z, w1.w};
#pragma unroll
        for (int r = 0; r < 4; ++r)
#pragma unroll
          for (int c = 0; c < 8; ++c)
            acc[r][c] += av[r] * wv[c];
      }
    }

#pragma unroll
    for (int c = 0; c < 8; ++c) {
      const int kg = k0 + ((c < 4) ? (tx * 4 + c) : (64 + tx * 4 + (c - 4)));
      const float wn = wnorm[kg];
#pragma unroll
      for (int r = 0; r < 4; ++r) {
        float dist = (xn[r] + wn) - 2.0f * acc[r][c];
        if (dist < best[r] || (dist == best[r] && kg < bidx[r])) {
          best[r] = dist; bidx[r] = kg;
        }
      }
    }
  }

#pragma unroll
  for (int j = 0; j < 4; ++j) {
    float bd = best[j];
    int   bi = bidx[j];
#pragma unroll
    for (int off = 1; off < 16; off <<= 1) {
      float od = __shfl_xor(bd, off);
      int   oi = __shfl_xor(bi, off);
      if (od < bd || (od == bd && oi < bi)) { bd = od; bi = oi; }
    }
    if (tx == 0) sIdx[ty * 4 + j] = bi;
  }
  __syncthreads();

  const int hwl = tid & 63;
  const int wv  = tid >> 6;
  const int ksel = sIdx[hwl];
  const float* wrow = weight + (size_t)ksel * DDIM;
  float lsum = 0.f;
#pragma unroll 4
  for (int it = 0; it < 64; ++it) {
    int d = it * 4 + wv;
    size_t off = (size_t)d * HWSZ + hw0 + hwl;
    float x = lat_b[off];
    float qv = wrow[d];
    out[(size_t)b * DDIM * HWSZ + off] = qv;
    float df = qv - x;
    lsum += df * df;
  }
#pragma unroll
  for (int off = 1; off < 64; off <<= 1) lsum += __shfl_xor(lsum, off);
  if ((tid & 63) == 0) sRed[tid >> 6] = lsum;
  __syncthreads();
  if (tid == 0) {
    float t = sRed[0] + sRed[1] + sRed[2] + sRed[3];
    atomicAdd(out + (size_t)NROWS * DDIM, t * (1.0f / ((float)NROWS * (float)DDIM)));
  }
}

// ---------------------------------------------------------------------------
extern "C" void kernel_launch(void* const* d_in, const int* in_sizes, int n_in,
                              void* d_out, int out_size, void* d_ws, size_t ws_size,
                              hipStream_t stream) {
  const float* latent = (const float*)d_in[0];   // (32,256,32,32) f32
  const float* weight = (const float*)d_in[1];   // (1024,256)     f32
  float* out   = (float*)d_out;                  // 8388608 + 1 (loss)
  char*  ws    = (char*)d_ws;
  float* wnorm = (float*)(ws + WS_WNORM);

  vq_wnorm<<<KCODES / 4, 256, 0, stream>>>(weight, wnorm, out + (size_t)NROWS * DDIM);

  if (ws_size >= (size_t)WS_NEED_MFMA) {
    vq_prep <<<KCODES / 8, 256, 0, stream>>>(weight, ws);
    vq_mfma3<<<1024, 512, 0, stream>>>(latent, weight, ws, out);
    vq_fixc <<< 512, 256, 0, stream>>>(latent, weight, ws, out);
  } else if (ws_size >= (size_t)WS_NEED_F32) {
    unsigned long long* keys = (unsigned long long*)(ws + WS_KEYS);
    hipMemsetAsync(ws + WS_KEYS, 0xFF, (size_t)NROWS * 8, stream);
    vq_dist<<<2048, NT, 0, stream>>>(latent, weight, wnorm, keys);
    vq_emit<<< 512, 256, 0, stream>>>(latent, weight, keys, out);
  } else {
    vq_mono<<< 512, NT, 0, stream>>>(latent, weight, wnorm, out);
  }
}